// Round 1
// baseline (12776.286 us; speedup 1.0000x reference)
//
#include <hip/hip_runtime.h>
#include <stdint.h>
#include <math.h>

#define NN 50000          // nodes
#define NE 800000         // edges
#define NH 4              // heads

// ======================= JAX threefry2x32 (partitionable mode) =======================
__host__ __device__ inline void tf2x32(uint32_t k0, uint32_t k1,
                                       uint32_t x0, uint32_t x1,
                                       uint32_t& o0, uint32_t& o1)
{
    uint32_t ks2 = k0 ^ k1 ^ 0x1BD11BDAu;
    x0 += k0; x1 += k1;
#define TF_R(r) { x0 += x1; x1 = (x1 << (r)) | (x1 >> (32 - (r))); x1 ^= x0; }
    TF_R(13) TF_R(15) TF_R(26) TF_R(6)
    x0 += k1;  x1 += ks2 + 1u;
    TF_R(17) TF_R(29) TF_R(16) TF_R(24)
    x0 += ks2; x1 += k0 + 2u;
    TF_R(13) TF_R(15) TF_R(26) TF_R(6)
    x0 += k0;  x1 += k1 + 3u;
    TF_R(17) TF_R(29) TF_R(16) TF_R(24)
    x0 += k1;  x1 += ks2 + 4u;
    TF_R(13) TF_R(15) TF_R(26) TF_R(6)
    x0 += ks2; x1 += k0 + 5u;
#undef TF_R
    o0 = x0; o1 = x1;
}

// random_bits (32-bit) in partitionable mode: bits[i] = y0 ^ y1 of tf(key, (hi(i)=0, lo(i)=i))
__device__ inline uint32_t jax_bits32(uint32_t k0, uint32_t k1, uint32_t idx)
{
    uint32_t a, b;
    tf2x32(k0, k1, 0u, idx, a, b);
    return a ^ b;
}

__device__ inline float jax_u01(uint32_t bits)
{
    return __uint_as_float((bits >> 9) | 0x3f800000u) - 1.0f;
}

// XLA ErfInv32 (Giles 2012)
__device__ inline float erfinv_f(float x)
{
    float w = -log1pf(-x * x);
    float p;
    if (w < 5.0f) {
        w = w - 2.5f;
        p = 2.81022636e-08f;
        p = fmaf(p, w, 3.43273939e-07f);
        p = fmaf(p, w, -3.5233877e-06f);
        p = fmaf(p, w, -4.39150654e-06f);
        p = fmaf(p, w, 0.00021858087f);
        p = fmaf(p, w, -0.00125372503f);
        p = fmaf(p, w, -0.00417768164f);
        p = fmaf(p, w, 0.246640727f);
        p = fmaf(p, w, 1.50140941f);
    } else {
        w = sqrtf(w) - 3.0f;
        p = -0.000200214257f;
        p = fmaf(p, w, 0.000100950558f);
        p = fmaf(p, w, 0.00134934322f);
        p = fmaf(p, w, -0.00367342844f);
        p = fmaf(p, w, 0.00573950773f);
        p = fmaf(p, w, -0.0076224613f);
        p = fmaf(p, w, 0.00943887047f);
        p = fmaf(p, w, 1.00167406f);
        p = fmaf(p, w, 2.83297682f);
    }
    return p * x;
}

// ======================= float <-> orderable uint (for atomic max) =======================
__device__ inline uint32_t enc_f32(float f)
{
    uint32_t u = __float_as_uint(f);
    return (u & 0x80000000u) ? ~u : (u | 0x80000000u);
}
__device__ inline float dec_f32(uint32_t u)
{
    uint32_t b = (u & 0x80000000u) ? (u ^ 0x80000000u) : ~u;
    return __uint_as_float(b);
}
#define ENC_NEG_INF 0x007FFFFFu   // enc(-inf)

// ======================= kernels =======================
__global__ __launch_bounds__(256) void fill_u32_k(uint32_t* p, uint32_t v, int n)
{
    int i = blockIdx.x * blockDim.x + threadIdx.x;
    if (i < n) p[i] = v;
}

// C[b][i][c] = sum_k A[i][k] * W[b][k][c]; blockDim.x = Ncols, grid.x = NN/ROWS, grid.y = batch
template<int ROWS>
__global__ __launch_bounds__(128) void gemm_rows(const float* __restrict__ A,
                                                 const float* __restrict__ W,
                                                 float* __restrict__ C,
                                                 int K, int Ncols, int relu)
{
    extern __shared__ float lds[]; // ROWS*K
    const int b = blockIdx.y;
    const int row0 = blockIdx.x * ROWS;
    const int tid = threadIdx.x;
    const int total = ROWS * K;
    const float* Arow = A + (size_t)row0 * K;
    for (int i = tid; i < total; i += blockDim.x) lds[i] = Arow[i];
    __syncthreads();

    const float* Wb = W + (size_t)b * K * Ncols;
    float acc[ROWS];
#pragma unroll
    for (int r = 0; r < ROWS; r++) acc[r] = 0.0f;
    for (int k = 0; k < K; k++) {
        float wv = Wb[(size_t)k * Ncols + tid];
#pragma unroll
        for (int r = 0; r < ROWS; r++) acc[r] = fmaf(lds[r * K + k], wv, acc[r]);
    }
    float* Cb = C + (size_t)b * NN * Ncols;
#pragma unroll
    for (int r = 0; r < ROWS; r++) {
        float v = acc[r];
        if (relu) v = fmaxf(v, 0.0f);
        Cb[(size_t)(row0 + r) * Ncols + tid] = v;
    }
}

// per (edge, head): s = dot(q[dst],k[src]) * scale ; atomicMax segment max over dst
__global__ __launch_bounds__(256) void edge_scores_k(const float* __restrict__ q,
                                                     const float* __restrict__ k,
                                                     const int* __restrict__ src,
                                                     const int* __restrict__ dst,
                                                     float* __restrict__ s,
                                                     uint32_t* __restrict__ menc,
                                                     int dh, float scale)
{
    int idx = blockIdx.x * blockDim.x + threadIdx.x;
    if (idx >= NE * NH) return;
    int e = idx >> 2, h = idx & 3;
    int dn = dst[e], sn = src[e];
    int od = NH * dh;
    const float4* qp = (const float4*)(q + (size_t)dn * od + h * dh);
    const float4* kp = (const float4*)(k + (size_t)sn * od + h * dh);
    float acc = 0.0f;
    for (int i = 0; i < dh / 4; i++) {
        float4 a = qp[i], b = kp[i];
        acc = fmaf(a.x, b.x, acc); acc = fmaf(a.y, b.y, acc);
        acc = fmaf(a.z, b.z, acc); acc = fmaf(a.w, b.w, acc);
    }
    acc *= scale;
    s[idx] = acc;
    atomicMax(&menc[dn * NH + h], enc_f32(acc));
}

// per (edge, head): e = exp(s - m[dst]); denom[dst] += e  (in-place into s)
__global__ __launch_bounds__(256) void edge_exp_k(float* __restrict__ s,
                                                  const int* __restrict__ dst,
                                                  const uint32_t* __restrict__ menc,
                                                  float* __restrict__ denom)
{
    int idx = blockIdx.x * blockDim.x + threadIdx.x;
    if (idx >= NE * NH) return;
    int e = idx >> 2, h = idx & 3;
    int dn = dst[e];
    float m = dec_f32(menc[dn * NH + h]);
    float t = expf(s[idx] - m);
    s[idx] = t;
    unsafeAtomicAdd(&denom[dn * NH + h], t);
}

// per (edge, col/4): agg[dst] += (e/denom[dst]) * v[src]
__global__ __launch_bounds__(256) void edge_scatter_k(const float* __restrict__ s,
                                                      const float* __restrict__ denom,
                                                      const float* __restrict__ v,
                                                      const int* __restrict__ src,
                                                      const int* __restrict__ dst,
                                                      float* __restrict__ agg,
                                                      int dh)
{
    const int od = NH * dh;
    const int vec = od >> 2;
    int idx = blockIdx.x * blockDim.x + threadIdx.x;
    if (idx >= NE * vec) return;
    int e = idx / vec;
    int c = (idx % vec) * 4;
    int h = c / dh;
    int sn = src[e], dn = dst[e];
    float alpha = s[e * NH + h] / denom[dn * NH + h];
    float4 vv = *(const float4*)(v + (size_t)sn * od + c);
    float* ap = agg + (size_t)dn * od + c;
    unsafeAtomicAdd(ap + 0, alpha * vv.x);
    unsafeAtomicAdd(ap + 1, alpha * vv.y);
    unsafeAtomicAdd(ap + 2, alpha * vv.z);
    unsafeAtomicAdd(ap + 3, alpha * vv.w);
}

// rows of 128: y = relu(x / max(||x||,1e-12)); dropout keep = (u01 < 0.5), scale 2x
__global__ __launch_bounds__(256) void norm_relu_drop_k(const float* __restrict__ in,
                                                        float* __restrict__ out,
                                                        uint32_t k0, uint32_t k1)
{
    int row = blockIdx.x * 4 + (threadIdx.x >> 6);
    int lane = threadIdx.x & 63;
    if (row >= NN) return;
    const float* r = in + (size_t)row * 128;
    float a = r[lane], b = r[lane + 64];
    float ss = fmaf(a, a, b * b);
#pragma unroll
    for (int m = 32; m > 0; m >>= 1) ss += __shfl_xor(ss, m, 64);
    float d = fmaxf(sqrtf(ss), 1e-12f);
    float ya = fmaxf(a / d, 0.0f);
    float yb = fmaxf(b / d, 0.0f);
    uint32_t ia = (uint32_t)row * 128u + (uint32_t)lane;
    float ua = jax_u01(jax_bits32(k0, k1, ia));
    float ub = jax_u01(jax_bits32(k0, k1, ia + 64u));
    float* o = out + (size_t)row * 128;
    o[lane]      = (ua < 0.5f) ? ya * 2.0f : 0.0f;
    o[lane + 64] = (ub < 0.5f) ? yb * 2.0f : 0.0f;
}

// rows of 64: y = x / max(||x||,1e-12)
__global__ __launch_bounds__(256) void norm64_k(const float* __restrict__ in,
                                                float* __restrict__ out)
{
    int row = blockIdx.x * 4 + (threadIdx.x >> 6);
    int lane = threadIdx.x & 63;
    if (row >= NN) return;
    float a = in[(size_t)row * 64 + lane];
    float ss = a * a;
#pragma unroll
    for (int m = 32; m > 0; m >>= 1) ss += __shfl_xor(ss, m, 64);
    float d = fmaxf(sqrtf(ss), 1e-12f);
    out[(size_t)row * 64 + lane] = a / d;
}

// z = eps * (exp(logvar)+1e-12) + mu ; eps = sqrt(2)*erfinv(max(lo, 2*u01 + lo))
__global__ __launch_bounds__(256) void final_z_k(const float* __restrict__ mu,
                                                 const float* __restrict__ lv,
                                                 float* __restrict__ out,
                                                 uint32_t k0, uint32_t k1)
{
    int i = blockIdx.x * blockDim.x + threadIdx.x;
    if (i >= NN * 64) return;
    const float LO = -0.99999994f; // nextafter(-1, 0) in f32
    float u01 = jax_u01(jax_bits32(k0, k1, (uint32_t)i));
    float u = fmaxf(LO, fmaf(u01, 2.0f, LO));
    float eps = 1.41421354f * erfinv_f(u);
    float stdv = expf(lv[i]) + 1e-12f;
    out[i] = fmaf(eps, stdv, mu[i]);
}

// ======================= host side =======================
struct Bufs {
    float* qkv;   // 3 * NN * 128
    float* agg;   // NN * 128
    float* h1;    // NN * 128
    float* h2;    // NN * 128
    float* x;     // NN * 128
    float* s;     // NE * NH
    float* den;   // NN * NH
    uint32_t* menc; // NN * NH
    float* mu;    // NN * 64
    float* lv;    // NN * 64
};

static void run_gt_layer(const float* h_in, int K, int od,
                         const float* wqkv, const float* wo, bool relu,
                         float* h_out, const Bufs& B,
                         const int* src, const int* dst, hipStream_t stream)
{
    const int dh = od / NH;
    const float scale = 1.0f / sqrtf((float)dh);

    // q,k,v = h_in @ wqkv[0..2]
    dim3 gq(NN / 8, 3);
    gemm_rows<8><<<gq, od, 8 * K * sizeof(float), stream>>>(h_in, wqkv, B.qkv, K, od, 0);
    const float* q = B.qkv;
    const float* k = B.qkv + (size_t)NN * od;
    const float* v = B.qkv + 2 * (size_t)NN * od;

    // init segment buffers
    fill_u32_k<<<(NN * NH + 255) / 256, 256, 0, stream>>>(B.menc, ENC_NEG_INF, NN * NH);
    fill_u32_k<<<(NN * NH + 255) / 256, 256, 0, stream>>>((uint32_t*)B.den, 0u, NN * NH);
    fill_u32_k<<<(NN * od + 255) / 256, 256, 0, stream>>>((uint32_t*)B.agg, 0u, NN * od);

    edge_scores_k<<<(NE * NH + 255) / 256, 256, 0, stream>>>(q, k, src, dst, B.s, B.menc, dh, scale);
    edge_exp_k<<<(NE * NH + 255) / 256, 256, 0, stream>>>(B.s, dst, B.menc, B.den);
    const int vec = od / 4;
    edge_scatter_k<<<(NE * vec + 255) / 256, 256, 0, stream>>>(B.s, B.den, v, src, dst, B.agg, dh);

    // h_out = agg @ wo  (+relu)
    gemm_rows<8><<<dim3(NN / 8, 1), od, 8 * od * sizeof(float), stream>>>(B.agg, wo, h_out, od, od, relu ? 1 : 0);
}

extern "C" void kernel_launch(void* const* d_in, const int* in_sizes, int n_in,
                              void* d_out, int out_size, void* d_ws, size_t ws_size,
                              hipStream_t stream)
{
    const float* feat    = (const float*)d_in[0];
    const int*   src     = (const int*)d_in[1];
    const int*   dst     = (const int*)d_in[2];
    const float* wqkv1_0 = (const float*)d_in[3];
    const float* wqkv1_r = (const float*)d_in[4];
    const float* wo1     = (const float*)d_in[5];
    const float* wqkv2_0 = (const float*)d_in[6];
    const float* wqkv2_r = (const float*)d_in[7];
    const float* wo2     = (const float*)d_in[8];
    const float* wqkv3_0 = (const float*)d_in[9];
    const float* wqkv3_r = (const float*)d_in[10];
    const float* wo3     = (const float*)d_in[11];
    float* out = (float*)d_out;

    // ---- workspace carve (256B aligned) ----
    char* wp = (char*)d_ws;
    auto alloc = [&](size_t bytes) { char* p = wp; wp += (bytes + 255) & ~(size_t)255; return p; };
    Bufs B;
    B.qkv  = (float*)alloc((size_t)3 * NN * 128 * 4);
    B.agg  = (float*)alloc((size_t)NN * 128 * 4);
    B.h1   = (float*)alloc((size_t)NN * 128 * 4);
    B.h2   = (float*)alloc((size_t)NN * 128 * 4);
    B.x    = (float*)alloc((size_t)NN * 128 * 4);
    B.s    = (float*)alloc((size_t)NE * NH * 4);
    B.den  = (float*)alloc((size_t)NN * NH * 4);
    B.menc = (uint32_t*)alloc((size_t)NN * NH * 4);
    B.mu   = (float*)alloc((size_t)NN * 64 * 4);
    B.lv   = (float*)alloc((size_t)NN * 64 * 4);

    // ---- JAX keys: key(42) -> split (partitionable/foldlike) ----
    uint32_t kd0, kd1, ke0, ke1;
    tf2x32(0u, 42u, 0u, 0u, kd0, kd1); // kd = keys[0]
    tf2x32(0u, 42u, 0u, 1u, ke0, ke1); // ke = keys[1]

    // ---- gc1: 256->128, 128->128, 128->128 ----
    run_gt_layer(feat, 256, 128, wqkv1_0,                 wo1,                 true,  B.h1, B, src, dst, stream);
    run_gt_layer(B.h1, 128, 128, wqkv1_r,                 wo1 + 128 * 128,     true,  B.h2, B, src, dst, stream);
    run_gt_layer(B.h2, 128, 128, wqkv1_r + 3 * 128 * 128, wo1 + 2 * 128 * 128, false, B.h1, B, src, dst, stream);

    // x = dropout(relu(l2norm(h)))
    norm_relu_drop_k<<<NN / 4, 256, 0, stream>>>(B.h1, B.x, kd0, kd1);

    // ---- gc2 -> mu ----
    run_gt_layer(B.x,  128, 64, wqkv2_0,               wo2,               true,  B.h1, B, src, dst, stream);
    run_gt_layer(B.h1, 64,  64, wqkv2_r,               wo2 + 64 * 64,     true,  B.h2, B, src, dst, stream);
    run_gt_layer(B.h2, 64,  64, wqkv2_r + 3 * 64 * 64, wo2 + 2 * 64 * 64, false, B.h1, B, src, dst, stream);
    norm64_k<<<NN / 4, 256, 0, stream>>>(B.h1, B.mu);

    // ---- gc3 -> logvar ----
    run_gt_layer(B.x,  128, 64, wqkv3_0,               wo3,               true,  B.h1, B, src, dst, stream);
    run_gt_layer(B.h1, 64,  64, wqkv3_r,               wo3 + 64 * 64,     true,  B.h2, B, src, dst, stream);
    run_gt_layer(B.h2, 64,  64, wqkv3_r + 3 * 64 * 64, wo3 + 2 * 64 * 64, false, B.h1, B, src, dst, stream);
    norm64_k<<<NN / 4, 256, 0, stream>>>(B.h1, B.lv);

    // ---- z = eps * (exp(logvar)+1e-12) + mu ----
    final_z_k<<<(NN * 64 + 255) / 256, 256, 0, stream>>>(B.mu, B.lv, out, ke0, ke1);
}

// Round 2
// 2667.532 us; speedup vs baseline: 4.7896x; 4.7896x over previous
//
#include <hip/hip_runtime.h>
#include <stdint.h>
#include <math.h>

#define NN 50000          // nodes
#define NE 800000         // edges
#define NH 4              // heads

// ======================= JAX threefry2x32 (partitionable mode) =======================
__host__ __device__ inline void tf2x32(uint32_t k0, uint32_t k1,
                                       uint32_t x0, uint32_t x1,
                                       uint32_t& o0, uint32_t& o1)
{
    uint32_t ks2 = k0 ^ k1 ^ 0x1BD11BDAu;
    x0 += k0; x1 += k1;
#define TF_R(r) { x0 += x1; x1 = (x1 << (r)) | (x1 >> (32 - (r))); x1 ^= x0; }
    TF_R(13) TF_R(15) TF_R(26) TF_R(6)
    x0 += k1;  x1 += ks2 + 1u;
    TF_R(17) TF_R(29) TF_R(16) TF_R(24)
    x0 += ks2; x1 += k0 + 2u;
    TF_R(13) TF_R(15) TF_R(26) TF_R(6)
    x0 += k0;  x1 += k1 + 3u;
    TF_R(17) TF_R(29) TF_R(16) TF_R(24)
    x0 += k1;  x1 += ks2 + 4u;
    TF_R(13) TF_R(15) TF_R(26) TF_R(6)
    x0 += ks2; x1 += k0 + 5u;
#undef TF_R
    o0 = x0; o1 = x1;
}

__device__ inline uint32_t jax_bits32(uint32_t k0, uint32_t k1, uint32_t idx)
{
    uint32_t a, b;
    tf2x32(k0, k1, 0u, idx, a, b);
    return a ^ b;
}

__device__ inline float jax_u01(uint32_t bits)
{
    return __uint_as_float((bits >> 9) | 0x3f800000u) - 1.0f;
}

// XLA ErfInv32 (Giles 2012)
__device__ inline float erfinv_f(float x)
{
    float w = -log1pf(-x * x);
    float p;
    if (w < 5.0f) {
        w = w - 2.5f;
        p = 2.81022636e-08f;
        p = fmaf(p, w, 3.43273939e-07f);
        p = fmaf(p, w, -3.5233877e-06f);
        p = fmaf(p, w, -4.39150654e-06f);
        p = fmaf(p, w, 0.00021858087f);
        p = fmaf(p, w, -0.00125372503f);
        p = fmaf(p, w, -0.00417768164f);
        p = fmaf(p, w, 0.246640727f);
        p = fmaf(p, w, 1.50140941f);
    } else {
        w = sqrtf(w) - 3.0f;
        p = -0.000200214257f;
        p = fmaf(p, w, 0.000100950558f);
        p = fmaf(p, w, 0.00134934322f);
        p = fmaf(p, w, -0.00367342844f);
        p = fmaf(p, w, 0.00573950773f);
        p = fmaf(p, w, -0.0076224613f);
        p = fmaf(p, w, 0.00943887047f);
        p = fmaf(p, w, 1.00167406f);
        p = fmaf(p, w, 2.83297682f);
    }
    return p * x;
}

// ======================= utility kernels =======================
__global__ __launch_bounds__(256) void fill_u32_k(uint32_t* p, uint32_t v, int n)
{
    int i = blockIdx.x * blockDim.x + threadIdx.x;
    if (i < n) p[i] = v;
}

// ======================= CSR build (once per launch) =======================
__global__ __launch_bounds__(256) void hist_k(const int* __restrict__ dst, int* __restrict__ deg)
{
    int e = blockIdx.x * blockDim.x + threadIdx.x;
    if (e < NE) atomicAdd(&deg[dst[e]], 1);
}

#define SCAN_CHUNK 1024
#define SCAN_NBLK  ((NN + SCAN_CHUNK - 1) / SCAN_CHUNK)   // 49

// per-chunk exclusive scan; block = 256 threads x 4 items
__global__ __launch_bounds__(256) void scan1_k(const int* __restrict__ deg,
                                               int* __restrict__ rowptr,
                                               int* __restrict__ bsums)
{
    __shared__ int lds[256];
    int b = blockIdx.x, t = threadIdx.x;
    int base = b * SCAN_CHUNK + t * 4;
    int v0 = (base + 0 < NN) ? deg[base + 0] : 0;
    int v1 = (base + 1 < NN) ? deg[base + 1] : 0;
    int v2 = (base + 2 < NN) ? deg[base + 2] : 0;
    int v3 = (base + 3 < NN) ? deg[base + 3] : 0;
    int s = v0 + v1 + v2 + v3;
    lds[t] = s;
    __syncthreads();
    for (int off = 1; off < 256; off <<= 1) {
        int x = (t >= off) ? lds[t - off] : 0;
        __syncthreads();
        lds[t] += x;
        __syncthreads();
    }
    int excl = lds[t] - s;      // exclusive prefix within chunk
    if (base + 0 < NN) rowptr[base + 0] = excl;
    if (base + 1 < NN) rowptr[base + 1] = excl + v0;
    if (base + 2 < NN) rowptr[base + 2] = excl + v0 + v1;
    if (base + 3 < NN) rowptr[base + 3] = excl + v0 + v1 + v2;
    if (t == 255) bsums[b] = lds[255];
}

__global__ void scan2_k(int* bsums)
{
    if (threadIdx.x == 0 && blockIdx.x == 0) {
        int run = 0;
        for (int i = 0; i < SCAN_NBLK; i++) { int t = bsums[i]; bsums[i] = run; run += t; }
    }
}

__global__ __launch_bounds__(256) void scan3_k(int* __restrict__ rowptr,
                                               const int* __restrict__ bsums,
                                               int* __restrict__ cursor)
{
    int i = blockIdx.x * blockDim.x + threadIdx.x;
    if (i < NN) {
        int r = rowptr[i] + bsums[i / SCAN_CHUNK];
        rowptr[i] = r;
        cursor[i] = r;
    }
    if (i == 0) rowptr[NN] = NE;
}

__global__ __launch_bounds__(256) void csr_scatter_k(const int* __restrict__ src,
                                                     const int* __restrict__ dst,
                                                     int* __restrict__ cursor,
                                                     int* __restrict__ esrc)
{
    int e = blockIdx.x * blockDim.x + threadIdx.x;
    if (e >= NE) return;
    int d = dst[e];
    int pos = atomicAdd(&cursor[d], 1);
    esrc[pos] = src[e];
}

// ======================= dense GEMM (row-block LDS) =======================
// C[b][i][c] = sum_k A[i][k] * W[b][k][c]; blockDim.x = Ncols, grid.x = NN/ROWS, grid.y = batch
template<int ROWS>
__global__ __launch_bounds__(128) void gemm_rows(const float* __restrict__ A,
                                                 const float* __restrict__ W,
                                                 float* __restrict__ C,
                                                 int K, int Ncols, int relu)
{
    extern __shared__ float lds[]; // ROWS*K
    const int b = blockIdx.y;
    const int row0 = blockIdx.x * ROWS;
    const int tid = threadIdx.x;
    const int total = ROWS * K;
    const float* Arow = A + (size_t)row0 * K;
    for (int i = tid; i < total; i += blockDim.x) lds[i] = Arow[i];
    __syncthreads();

    const float* Wb = W + (size_t)b * K * Ncols;
    float acc[ROWS];
#pragma unroll
    for (int r = 0; r < ROWS; r++) acc[r] = 0.0f;
    for (int k = 0; k < K; k++) {
        float wv = Wb[(size_t)k * Ncols + tid];
#pragma unroll
        for (int r = 0; r < ROWS; r++) acc[r] = fmaf(lds[r * K + k], wv, acc[r]);
    }
    float* Cb = C + (size_t)b * NN * Ncols;
#pragma unroll
    for (int r = 0; r < ROWS; r++) {
        float v = acc[r];
        if (relu) v = fmaxf(v, 0.0f);
        Cb[(size_t)(row0 + r) * Ncols + tid] = v;
    }
}

// ======================= fused per-(node,head) attention (no atomics) =======================
// thread t -> node n = t>>2, head h = t&3. Streams CSR incoming edges with
// online softmax; agg written exactly once.
template<int DH>
__global__ __launch_bounds__(256) void fused_attn_k(const float* __restrict__ q,
                                                    const float* __restrict__ k,
                                                    const float* __restrict__ v,
                                                    const int* __restrict__ rowptr,
                                                    const int* __restrict__ esrc,
                                                    float* __restrict__ agg,
                                                    float scale)
{
    int t = blockIdx.x * blockDim.x + threadIdx.x;
    if (t >= NN * NH) return;
    int n = t >> 2, h = t & 3;
    const int od = NH * DH;
    constexpr int V4 = DH / 4;

    const float4* qp = (const float4*)(q + (size_t)n * od + h * DH);
    float4 qf[V4];
#pragma unroll
    for (int i = 0; i < V4; i++) qf[i] = qp[i];

    float4 acc[V4];
#pragma unroll
    for (int i = 0; i < V4; i++) acc[i] = make_float4(0.f, 0.f, 0.f, 0.f);

    float m = -INFINITY, l = 0.0f;
    int j0 = rowptr[n];
    int j1 = rowptr[n + 1];
    for (int j = j0; j < j1; ++j) {
        int sn = esrc[j];
        const float4* kp = (const float4*)(k + (size_t)sn * od + h * DH);
        float s = 0.0f;
#pragma unroll
        for (int i = 0; i < V4; i++) {
            float4 kk = kp[i];
            s = fmaf(qf[i].x, kk.x, s); s = fmaf(qf[i].y, kk.y, s);
            s = fmaf(qf[i].z, kk.z, s); s = fmaf(qf[i].w, kk.w, s);
        }
        s *= scale;
        float mn = fmaxf(m, s);
        float corr = expf(m - mn);   // first iter: exp(-inf)=0
        float p = expf(s - mn);
        l = l * corr + p;
        const float4* vp = (const float4*)(v + (size_t)sn * od + h * DH);
#pragma unroll
        for (int i = 0; i < V4; i++) {
            float4 vv = vp[i];
            acc[i].x = fmaf(p, vv.x, acc[i].x * corr);
            acc[i].y = fmaf(p, vv.y, acc[i].y * corr);
            acc[i].z = fmaf(p, vv.z, acc[i].z * corr);
            acc[i].w = fmaf(p, vv.w, acc[i].w * corr);
        }
        m = mn;
    }
    float inv = (l > 0.0f) ? 1.0f / l : 0.0f;
    float4* op = (float4*)(agg + (size_t)n * od + h * DH);
#pragma unroll
    for (int i = 0; i < V4; i++)
        op[i] = make_float4(acc[i].x * inv, acc[i].y * inv, acc[i].z * inv, acc[i].w * inv);
}

// ======================= norms / dropout / reparam =======================
__global__ __launch_bounds__(256) void norm_relu_drop_k(const float* __restrict__ in,
                                                        float* __restrict__ out,
                                                        uint32_t k0, uint32_t k1)
{
    int row = blockIdx.x * 4 + (threadIdx.x >> 6);
    int lane = threadIdx.x & 63;
    if (row >= NN) return;
    const float* r = in + (size_t)row * 128;
    float a = r[lane], b = r[lane + 64];
    float ss = fmaf(a, a, b * b);
#pragma unroll
    for (int m = 32; m > 0; m >>= 1) ss += __shfl_xor(ss, m, 64);
    float d = fmaxf(sqrtf(ss), 1e-12f);
    float ya = fmaxf(a / d, 0.0f);
    float yb = fmaxf(b / d, 0.0f);
    uint32_t ia = (uint32_t)row * 128u + (uint32_t)lane;
    float ua = jax_u01(jax_bits32(k0, k1, ia));
    float ub = jax_u01(jax_bits32(k0, k1, ia + 64u));
    float* o = out + (size_t)row * 128;
    o[lane]      = (ua < 0.5f) ? ya * 2.0f : 0.0f;
    o[lane + 64] = (ub < 0.5f) ? yb * 2.0f : 0.0f;
}

__global__ __launch_bounds__(256) void norm64_k(const float* __restrict__ in,
                                                float* __restrict__ out)
{
    int row = blockIdx.x * 4 + (threadIdx.x >> 6);
    int lane = threadIdx.x & 63;
    if (row >= NN) return;
    float a = in[(size_t)row * 64 + lane];
    float ss = a * a;
#pragma unroll
    for (int m = 32; m > 0; m >>= 1) ss += __shfl_xor(ss, m, 64);
    float d = fmaxf(sqrtf(ss), 1e-12f);
    out[(size_t)row * 64 + lane] = a / d;
}

__global__ __launch_bounds__(256) void final_z_k(const float* __restrict__ mu,
                                                 const float* __restrict__ lv,
                                                 float* __restrict__ out,
                                                 uint32_t k0, uint32_t k1)
{
    int i = blockIdx.x * blockDim.x + threadIdx.x;
    if (i >= NN * 64) return;
    const float LO = -0.99999994f; // nextafter(-1, 0) in f32
    float u01 = jax_u01(jax_bits32(k0, k1, (uint32_t)i));
    float u = fmaxf(LO, fmaf(u01, 2.0f, LO));
    float eps = 1.41421354f * erfinv_f(u);
    float stdv = expf(lv[i]) + 1e-12f;
    out[i] = fmaf(eps, stdv, mu[i]);
}

// ======================= host side =======================
struct Bufs {
    float* qkv;   // 3 * NN * 128
    float* agg;   // NN * 128
    float* h1;
    float* h2;
    float* x;
    float* mu;
    float* lv;
    int* rowptr;  // NN+1
    int* cursor;  // NN (also deg)
    int* bsums;   // SCAN_NBLK
    int* esrc;    // NE
};

static void run_gt_layer(const float* h_in, int K, int od,
                         const float* wqkv, const float* wo, bool relu,
                         float* h_out, const Bufs& B, hipStream_t stream)
{
    const int dh = od / NH;
    const float scale = 1.0f / sqrtf((float)dh);

    dim3 gq(NN / 8, 3);
    gemm_rows<8><<<gq, od, 8 * K * sizeof(float), stream>>>(h_in, wqkv, B.qkv, K, od, 0);
    const float* q = B.qkv;
    const float* k = B.qkv + (size_t)NN * od;
    const float* v = B.qkv + 2 * (size_t)NN * od;

    int grid = (NN * NH + 255) / 256;
    if (dh == 32)
        fused_attn_k<32><<<grid, 256, 0, stream>>>(q, k, v, B.rowptr, B.esrc, B.agg, scale);
    else
        fused_attn_k<16><<<grid, 256, 0, stream>>>(q, k, v, B.rowptr, B.esrc, B.agg, scale);

    gemm_rows<8><<<dim3(NN / 8, 1), od, 8 * od * sizeof(float), stream>>>(B.agg, wo, h_out, od, od, relu ? 1 : 0);
}

extern "C" void kernel_launch(void* const* d_in, const int* in_sizes, int n_in,
                              void* d_out, int out_size, void* d_ws, size_t ws_size,
                              hipStream_t stream)
{
    const float* feat    = (const float*)d_in[0];
    const int*   src     = (const int*)d_in[1];
    const int*   dst     = (const int*)d_in[2];
    const float* wqkv1_0 = (const float*)d_in[3];
    const float* wqkv1_r = (const float*)d_in[4];
    const float* wo1     = (const float*)d_in[5];
    const float* wqkv2_0 = (const float*)d_in[6];
    const float* wqkv2_r = (const float*)d_in[7];
    const float* wo2     = (const float*)d_in[8];
    const float* wqkv3_0 = (const float*)d_in[9];
    const float* wqkv3_r = (const float*)d_in[10];
    const float* wo3     = (const float*)d_in[11];
    float* out = (float*)d_out;

    char* wp = (char*)d_ws;
    auto alloc = [&](size_t bytes) { char* p = wp; wp += (bytes + 255) & ~(size_t)255; return p; };
    Bufs B;
    B.qkv    = (float*)alloc((size_t)3 * NN * 128 * 4);
    B.agg    = (float*)alloc((size_t)NN * 128 * 4);
    B.h1     = (float*)alloc((size_t)NN * 128 * 4);
    B.h2     = (float*)alloc((size_t)NN * 128 * 4);
    B.x      = (float*)alloc((size_t)NN * 128 * 4);
    B.mu     = (float*)alloc((size_t)NN * 64 * 4);
    B.lv     = (float*)alloc((size_t)NN * 64 * 4);
    B.rowptr = (int*)alloc((size_t)(NN + 1) * 4);
    B.cursor = (int*)alloc((size_t)NN * 4);
    B.bsums  = (int*)alloc((size_t)SCAN_NBLK * 4);
    B.esrc   = (int*)alloc((size_t)NE * 4);

    // ---- CSR build (deg -> rowptr -> permuted src), once per launch ----
    fill_u32_k<<<(NN + 255) / 256, 256, 0, stream>>>((uint32_t*)B.cursor, 0u, NN); // cursor as deg
    hist_k<<<(NE + 255) / 256, 256, 0, stream>>>(dst, B.cursor);
    scan1_k<<<SCAN_NBLK, 256, 0, stream>>>(B.cursor, B.rowptr, B.bsums);
    scan2_k<<<1, 64, 0, stream>>>(B.bsums);
    scan3_k<<<(NN + 255) / 256, 256, 0, stream>>>(B.rowptr, B.bsums, B.cursor);
    csr_scatter_k<<<(NE + 255) / 256, 256, 0, stream>>>(src, dst, B.cursor, B.esrc);

    // ---- JAX keys: key(42) -> split (partitionable/foldlike) ----
    uint32_t kd0, kd1, ke0, ke1;
    tf2x32(0u, 42u, 0u, 0u, kd0, kd1);
    tf2x32(0u, 42u, 0u, 1u, ke0, ke1);

    // ---- gc1: 256->128, 128->128, 128->128 ----
    run_gt_layer(feat, 256, 128, wqkv1_0,                 wo1,                 true,  B.h1, B, stream);
    run_gt_layer(B.h1, 128, 128, wqkv1_r,                 wo1 + 128 * 128,     true,  B.h2, B, stream);
    run_gt_layer(B.h2, 128, 128, wqkv1_r + 3 * 128 * 128, wo1 + 2 * 128 * 128, false, B.h1, B, stream);

    norm_relu_drop_k<<<NN / 4, 256, 0, stream>>>(B.h1, B.x, kd0, kd1);

    // ---- gc2 -> mu ----
    run_gt_layer(B.x,  128, 64, wqkv2_0,               wo2,               true,  B.h1, B, stream);
    run_gt_layer(B.h1, 64,  64, wqkv2_r,               wo2 + 64 * 64,     true,  B.h2, B, stream);
    run_gt_layer(B.h2, 64,  64, wqkv2_r + 3 * 64 * 64, wo2 + 2 * 64 * 64, false, B.h1, B, stream);
    norm64_k<<<NN / 4, 256, 0, stream>>>(B.h1, B.mu);

    // ---- gc3 -> logvar ----
    run_gt_layer(B.x,  128, 64, wqkv3_0,               wo3,               true,  B.h1, B, stream);
    run_gt_layer(B.h1, 64,  64, wqkv3_r,               wo3 + 64 * 64,     true,  B.h2, B, stream);
    run_gt_layer(B.h2, 64,  64, wqkv3_r + 3 * 64 * 64, wo3 + 2 * 64 * 64, false, B.h1, B, stream);
    norm64_k<<<NN / 4, 256, 0, stream>>>(B.h1, B.lv);

    final_z_k<<<(NN * 64 + 255) / 256, 256, 0, stream>>>(B.mu, B.lv, out, ke0, ke1);
}

// Round 3
// 2071.156 us; speedup vs baseline: 6.1687x; 1.2879x over previous
//
#include <hip/hip_runtime.h>
#include <stdint.h>
#include <math.h>

#define NN 50000          // nodes
#define NE 800000         // edges
#define NH 4              // heads

// ======================= JAX threefry2x32 (partitionable mode) =======================
__host__ __device__ inline void tf2x32(uint32_t k0, uint32_t k1,
                                       uint32_t x0, uint32_t x1,
                                       uint32_t& o0, uint32_t& o1)
{
    uint32_t ks2 = k0 ^ k1 ^ 0x1BD11BDAu;
    x0 += k0; x1 += k1;
#define TF_R(r) { x0 += x1; x1 = (x1 << (r)) | (x1 >> (32 - (r))); x1 ^= x0; }
    TF_R(13) TF_R(15) TF_R(26) TF_R(6)
    x0 += k1;  x1 += ks2 + 1u;
    TF_R(17) TF_R(29) TF_R(16) TF_R(24)
    x0 += ks2; x1 += k0 + 2u;
    TF_R(13) TF_R(15) TF_R(26) TF_R(6)
    x0 += k0;  x1 += k1 + 3u;
    TF_R(17) TF_R(29) TF_R(16) TF_R(24)
    x0 += k1;  x1 += ks2 + 4u;
    TF_R(13) TF_R(15) TF_R(26) TF_R(6)
    x0 += ks2; x1 += k0 + 5u;
#undef TF_R
    o0 = x0; o1 = x1;
}

__device__ inline uint32_t jax_bits32(uint32_t k0, uint32_t k1, uint32_t idx)
{
    uint32_t a, b;
    tf2x32(k0, k1, 0u, idx, a, b);
    return a ^ b;
}

__device__ inline float jax_u01(uint32_t bits)
{
    return __uint_as_float((bits >> 9) | 0x3f800000u) - 1.0f;
}

// XLA ErfInv32 (Giles 2012)
__device__ inline float erfinv_f(float x)
{
    float w = -log1pf(-x * x);
    float p;
    if (w < 5.0f) {
        w = w - 2.5f;
        p = 2.81022636e-08f;
        p = fmaf(p, w, 3.43273939e-07f);
        p = fmaf(p, w, -3.5233877e-06f);
        p = fmaf(p, w, -4.39150654e-06f);
        p = fmaf(p, w, 0.00021858087f);
        p = fmaf(p, w, -0.00125372503f);
        p = fmaf(p, w, -0.00417768164f);
        p = fmaf(p, w, 0.246640727f);
        p = fmaf(p, w, 1.50140941f);
    } else {
        w = sqrtf(w) - 3.0f;
        p = -0.000200214257f;
        p = fmaf(p, w, 0.000100950558f);
        p = fmaf(p, w, 0.00134934322f);
        p = fmaf(p, w, -0.00367342844f);
        p = fmaf(p, w, 0.00573950773f);
        p = fmaf(p, w, -0.0076224613f);
        p = fmaf(p, w, 0.00943887047f);
        p = fmaf(p, w, 1.00167406f);
        p = fmaf(p, w, 2.83297682f);
    }
    return p * x;
}

// ======================= utility kernels =======================
__global__ __launch_bounds__(256) void fill_u32_k(uint32_t* p, uint32_t v, int n)
{
    int i = blockIdx.x * blockDim.x + threadIdx.x;
    if (i < n) p[i] = v;
}

// ======================= CSR build (once per launch) =======================
__global__ __launch_bounds__(256) void hist_k(const int* __restrict__ dst, int* __restrict__ deg)
{
    int e = blockIdx.x * blockDim.x + threadIdx.x;
    if (e < NE) atomicAdd(&deg[dst[e]], 1);
}

#define SCAN_CHUNK 1024
#define SCAN_NBLK  ((NN + SCAN_CHUNK - 1) / SCAN_CHUNK)   // 49

__global__ __launch_bounds__(256) void scan1_k(const int* __restrict__ deg,
                                               int* __restrict__ rowptr,
                                               int* __restrict__ bsums)
{
    __shared__ int lds[256];
    int b = blockIdx.x, t = threadIdx.x;
    int base = b * SCAN_CHUNK + t * 4;
    int v0 = (base + 0 < NN) ? deg[base + 0] : 0;
    int v1 = (base + 1 < NN) ? deg[base + 1] : 0;
    int v2 = (base + 2 < NN) ? deg[base + 2] : 0;
    int v3 = (base + 3 < NN) ? deg[base + 3] : 0;
    int s = v0 + v1 + v2 + v3;
    lds[t] = s;
    __syncthreads();
    for (int off = 1; off < 256; off <<= 1) {
        int x = (t >= off) ? lds[t - off] : 0;
        __syncthreads();
        lds[t] += x;
        __syncthreads();
    }
    int excl = lds[t] - s;
    if (base + 0 < NN) rowptr[base + 0] = excl;
    if (base + 1 < NN) rowptr[base + 1] = excl + v0;
    if (base + 2 < NN) rowptr[base + 2] = excl + v0 + v1;
    if (base + 3 < NN) rowptr[base + 3] = excl + v0 + v1 + v2;
    if (t == 255) bsums[b] = lds[255];
}

__global__ void scan2_k(int* bsums)
{
    if (threadIdx.x == 0 && blockIdx.x == 0) {
        int run = 0;
        for (int i = 0; i < SCAN_NBLK; i++) { int t = bsums[i]; bsums[i] = run; run += t; }
    }
}

__global__ __launch_bounds__(256) void scan3_k(int* __restrict__ rowptr,
                                               const int* __restrict__ bsums,
                                               int* __restrict__ cursor)
{
    int i = blockIdx.x * blockDim.x + threadIdx.x;
    if (i < NN) {
        int r = rowptr[i] + bsums[i / SCAN_CHUNK];
        rowptr[i] = r;
        cursor[i] = r;
    }
    if (i == 0) rowptr[NN] = NE;
}

__global__ __launch_bounds__(256) void csr_scatter_k(const int* __restrict__ src,
                                                     const int* __restrict__ dst,
                                                     int* __restrict__ cursor,
                                                     int* __restrict__ esrc)
{
    int e = blockIdx.x * blockDim.x + threadIdx.x;
    if (e >= NE) return;
    int d = dst[e];
    int pos = atomicAdd(&cursor[d], 1);
    esrc[pos] = src[e];
}

// ======================= tiled register-blocked fp32 GEMM =======================
// C[N][Ntot] = A[N][K] x W, where W is a batch of (Ntot/Cper) matrices, each
// [K][Cper] contiguous (qkv weights [3][K][C] fused along N). BM=BN=64, BK=32,
// 256 threads, 4x4 micro-tile per thread: 16 FMA per 2 ds_read_b128.
__global__ __launch_bounds__(256) void gemm_tile_k(const float* __restrict__ A,
                                                   const float* __restrict__ W,
                                                   float* __restrict__ Cout,
                                                   int N, int K, int Cper, int Ntot,
                                                   int relu)
{
    __shared__ float As[32][65];   // [k][m], +1 pad for transposed writes
    __shared__ float Bs[32][64];   // [k][n]

    const int tid = threadIdx.x;
    const int row0 = blockIdx.x * 64;
    const int nt0 = blockIdx.y * 64;
    const int b   = nt0 / Cper;                    // Cper % 64 == 0 -> tile within one matrix
    const int c0  = nt0 - b * Cper;
    const float* Wb = W + (size_t)b * K * Cper + c0;

    const int m0 = (tid >> 4) << 2;   // 0..60 (wave: {0,4,8,12} -> As read is broadcast)
    const int n0 = (tid & 15) << 2;   // 0..60

    // A-load mapping: thread -> (row ar, k-offset ak), 2x float4 per k-tile
    const int ar = tid >> 2;          // 0..63
    const int ak = (tid & 3) << 3;    // 0,8,16,24
    int arow = row0 + ar; if (arow >= N) arow = N - 1;   // clamp (guarded at store)
    const float* Arow = A + (size_t)arow * K;

    // B-load mapping: float4 id i -> (k = i>>4, n = (i&15)*4), 2 per thread
    const int bk0 = tid >> 4,        bn0 = (tid & 15) << 2;
    const int bk1 = (tid + 256) >> 4, bn1 = bn0;

    float acc[4][4] = {};

    for (int k0 = 0; k0 < K; k0 += 32) {
        float4 a0 = *(const float4*)(Arow + k0 + ak);
        float4 a1 = *(const float4*)(Arow + k0 + ak + 4);
        float4 b0 = *(const float4*)(Wb + (size_t)(k0 + bk0) * Cper + bn0);
        float4 b1 = *(const float4*)(Wb + (size_t)(k0 + bk1) * Cper + bn1);
        __syncthreads();   // previous tile fully consumed
        As[ak + 0][ar] = a0.x; As[ak + 1][ar] = a0.y; As[ak + 2][ar] = a0.z; As[ak + 3][ar] = a0.w;
        As[ak + 4][ar] = a1.x; As[ak + 5][ar] = a1.y; As[ak + 6][ar] = a1.z; As[ak + 7][ar] = a1.w;
        *(float4*)&Bs[bk0][bn0] = b0;
        *(float4*)&Bs[bk1][bn1] = b1;
        __syncthreads();
#pragma unroll
        for (int kk = 0; kk < 32; kk++) {
            float4 av = *(const float4*)&As[kk][m0];
            float4 bv = *(const float4*)&Bs[kk][n0];
            acc[0][0] = fmaf(av.x, bv.x, acc[0][0]); acc[0][1] = fmaf(av.x, bv.y, acc[0][1]);
            acc[0][2] = fmaf(av.x, bv.z, acc[0][2]); acc[0][3] = fmaf(av.x, bv.w, acc[0][3]);
            acc[1][0] = fmaf(av.y, bv.x, acc[1][0]); acc[1][1] = fmaf(av.y, bv.y, acc[1][1]);
            acc[1][2] = fmaf(av.y, bv.z, acc[1][2]); acc[1][3] = fmaf(av.y, bv.w, acc[1][3]);
            acc[2][0] = fmaf(av.z, bv.x, acc[2][0]); acc[2][1] = fmaf(av.z, bv.y, acc[2][1]);
            acc[2][2] = fmaf(av.z, bv.z, acc[2][2]); acc[2][3] = fmaf(av.z, bv.w, acc[2][3]);
            acc[3][0] = fmaf(av.w, bv.x, acc[3][0]); acc[3][1] = fmaf(av.w, bv.y, acc[3][1]);
            acc[3][2] = fmaf(av.w, bv.z, acc[3][2]); acc[3][3] = fmaf(av.w, bv.w, acc[3][3]);
        }
    }

#pragma unroll
    for (int i = 0; i < 4; i++) {
        int grow = row0 + m0 + i;
        if (grow < N) {
            float4 o;
            o.x = acc[i][0]; o.y = acc[i][1]; o.z = acc[i][2]; o.w = acc[i][3];
            if (relu) {
                o.x = fmaxf(o.x, 0.f); o.y = fmaxf(o.y, 0.f);
                o.z = fmaxf(o.z, 0.f); o.w = fmaxf(o.w, 0.f);
            }
            *(float4*)(Cout + (size_t)grow * Ntot + nt0 + n0) = o;
        }
    }
}

// ======================= fused per-(node,head) attention (no atomics) =======================
// qkv layout: [N][3*OD] rows: [q(OD) | k(OD) | v(OD)]
template<int DH>
__global__ __launch_bounds__(256) void fused_attn_k(const float* __restrict__ qkv,
                                                    const int* __restrict__ rowptr,
                                                    const int* __restrict__ esrc,
                                                    float* __restrict__ agg,
                                                    float scale)
{
    int t = blockIdx.x * blockDim.x + threadIdx.x;
    if (t >= NN * NH) return;
    int n = t >> 2, h = t & 3;
    constexpr int OD = NH * DH;
    constexpr int STR = 3 * OD;
    constexpr int V4 = DH / 4;

    const float4* qp = (const float4*)(qkv + (size_t)n * STR + h * DH);
    float4 qf[V4];
#pragma unroll
    for (int i = 0; i < V4; i++) qf[i] = qp[i];

    float4 acc[V4];
#pragma unroll
    for (int i = 0; i < V4; i++) acc[i] = make_float4(0.f, 0.f, 0.f, 0.f);

    float m = -INFINITY, l = 0.0f;
    int j0 = rowptr[n];
    int j1 = rowptr[n + 1];
    for (int j = j0; j < j1; ++j) {
        int sn = esrc[j];
        const float* rowb = qkv + (size_t)sn * STR + h * DH;
        const float4* kp = (const float4*)(rowb + OD);
        float s = 0.0f;
#pragma unroll
        for (int i = 0; i < V4; i++) {
            float4 kk = kp[i];
            s = fmaf(qf[i].x, kk.x, s); s = fmaf(qf[i].y, kk.y, s);
            s = fmaf(qf[i].z, kk.z, s); s = fmaf(qf[i].w, kk.w, s);
        }
        s *= scale;
        float mn = fmaxf(m, s);
        float corr = expf(m - mn);
        float p = expf(s - mn);
        l = l * corr + p;
        const float4* vp = (const float4*)(rowb + 2 * OD);
#pragma unroll
        for (int i = 0; i < V4; i++) {
            float4 vv = vp[i];
            acc[i].x = fmaf(p, vv.x, acc[i].x * corr);
            acc[i].y = fmaf(p, vv.y, acc[i].y * corr);
            acc[i].z = fmaf(p, vv.z, acc[i].z * corr);
            acc[i].w = fmaf(p, vv.w, acc[i].w * corr);
        }
        m = mn;
    }
    float inv = (l > 0.0f) ? 1.0f / l : 0.0f;
    float4* op = (float4*)(agg + (size_t)n * OD + h * DH);
#pragma unroll
    for (int i = 0; i < V4; i++)
        op[i] = make_float4(acc[i].x * inv, acc[i].y * inv, acc[i].z * inv, acc[i].w * inv);
}

// ======================= norms / dropout / reparam =======================
__global__ __launch_bounds__(256) void norm_relu_drop_k(const float* __restrict__ in,
                                                        float* __restrict__ out,
                                                        uint32_t k0, uint32_t k1)
{
    int row = blockIdx.x * 4 + (threadIdx.x >> 6);
    int lane = threadIdx.x & 63;
    if (row >= NN) return;
    const float* r = in + (size_t)row * 128;
    float a = r[lane], b = r[lane + 64];
    float ss = fmaf(a, a, b * b);
#pragma unroll
    for (int m = 32; m > 0; m >>= 1) ss += __shfl_xor(ss, m, 64);
    float d = fmaxf(sqrtf(ss), 1e-12f);
    float ya = fmaxf(a / d, 0.0f);
    float yb = fmaxf(b / d, 0.0f);
    uint32_t ia = (uint32_t)row * 128u + (uint32_t)lane;
    float ua = jax_u01(jax_bits32(k0, k1, ia));
    float ub = jax_u01(jax_bits32(k0, k1, ia + 64u));
    float* o = out + (size_t)row * 128;
    o[lane]      = (ua < 0.5f) ? ya * 2.0f : 0.0f;
    o[lane + 64] = (ub < 0.5f) ? yb * 2.0f : 0.0f;
}

__global__ __launch_bounds__(256) void norm64_k(const float* __restrict__ in,
                                                float* __restrict__ out)
{
    int row = blockIdx.x * 4 + (threadIdx.x >> 6);
    int lane = threadIdx.x & 63;
    if (row >= NN) return;
    float a = in[(size_t)row * 64 + lane];
    float ss = a * a;
#pragma unroll
    for (int m = 32; m > 0; m >>= 1) ss += __shfl_xor(ss, m, 64);
    float d = fmaxf(sqrtf(ss), 1e-12f);
    out[(size_t)row * 64 + lane] = a / d;
}

__global__ __launch_bounds__(256) void final_z_k(const float* __restrict__ mu,
                                                 const float* __restrict__ lv,
                                                 float* __restrict__ out,
                                                 uint32_t k0, uint32_t k1)
{
    int i = blockIdx.x * blockDim.x + threadIdx.x;
    if (i >= NN * 64) return;
    const float LO = -0.99999994f; // nextafter(-1, 0) in f32
    float u01 = jax_u01(jax_bits32(k0, k1, (uint32_t)i));
    float u = fmaxf(LO, fmaf(u01, 2.0f, LO));
    float eps = 1.41421354f * erfinv_f(u);
    float stdv = expf(lv[i]) + 1e-12f;
    out[i] = fmaf(eps, stdv, mu[i]);
}

// ======================= host side =======================
struct Bufs {
    float* qkv;   // NN * 384  ([N][3*OD] fused layout)
    float* agg;   // NN * 128
    float* h1;
    float* h2;
    float* x;
    float* mu;
    float* lv;
    int* rowptr;
    int* cursor;
    int* bsums;
    int* esrc;
};

static void run_gt_layer(const float* h_in, int K, int od,
                         const float* wqkv, const float* wo, bool relu,
                         float* h_out, const Bufs& B, hipStream_t stream)
{
    const int dh = od / NH;
    const float scale = 1.0f / sqrtf((float)dh);
    const int GX = (NN + 63) / 64;

    // qkv = h_in @ [wq|wk|wv]  -> [N][3*od]
    gemm_tile_k<<<dim3(GX, 3 * od / 64), 256, 0, stream>>>(h_in, wqkv, B.qkv, NN, K, od, 3 * od, 0);

    int grid = (NN * NH + 255) / 256;
    if (dh == 32)
        fused_attn_k<32><<<grid, 256, 0, stream>>>(B.qkv, B.rowptr, B.esrc, B.agg, scale);
    else
        fused_attn_k<16><<<grid, 256, 0, stream>>>(B.qkv, B.rowptr, B.esrc, B.agg, scale);

    // h_out = agg @ wo (+relu)
    gemm_tile_k<<<dim3(GX, od / 64), 256, 0, stream>>>(B.agg, wo, h_out, NN, od, od, od, relu ? 1 : 0);
}

extern "C" void kernel_launch(void* const* d_in, const int* in_sizes, int n_in,
                              void* d_out, int out_size, void* d_ws, size_t ws_size,
                              hipStream_t stream)
{
    const float* feat    = (const float*)d_in[0];
    const int*   src     = (const int*)d_in[1];
    const int*   dst     = (const int*)d_in[2];
    const float* wqkv1_0 = (const float*)d_in[3];
    const float* wqkv1_r = (const float*)d_in[4];
    const float* wo1     = (const float*)d_in[5];
    const float* wqkv2_0 = (const float*)d_in[6];
    const float* wqkv2_r = (const float*)d_in[7];
    const float* wo2     = (const float*)d_in[8];
    const float* wqkv3_0 = (const float*)d_in[9];
    const float* wqkv3_r = (const float*)d_in[10];
    const float* wo3     = (const float*)d_in[11];
    float* out = (float*)d_out;

    char* wp = (char*)d_ws;
    auto alloc = [&](size_t bytes) { char* p = wp; wp += (bytes + 255) & ~(size_t)255; return p; };
    Bufs B;
    B.qkv    = (float*)alloc((size_t)NN * 384 * 4);
    B.agg    = (float*)alloc((size_t)NN * 128 * 4);
    B.h1     = (float*)alloc((size_t)NN * 128 * 4);
    B.h2     = (float*)alloc((size_t)NN * 128 * 4);
    B.x      = (float*)alloc((size_t)NN * 128 * 4);
    B.mu     = (float*)alloc((size_t)NN * 64 * 4);
    B.lv     = (float*)alloc((size_t)NN * 64 * 4);
    B.rowptr = (int*)alloc((size_t)(NN + 1) * 4);
    B.cursor = (int*)alloc((size_t)NN * 4);
    B.bsums  = (int*)alloc((size_t)SCAN_NBLK * 4);
    B.esrc   = (int*)alloc((size_t)NE * 4);

    // ---- CSR build ----
    fill_u32_k<<<(NN + 255) / 256, 256, 0, stream>>>((uint32_t*)B.cursor, 0u, NN);
    hist_k<<<(NE + 255) / 256, 256, 0, stream>>>(dst, B.cursor);
    scan1_k<<<SCAN_NBLK, 256, 0, stream>>>(B.cursor, B.rowptr, B.bsums);
    scan2_k<<<1, 64, 0, stream>>>(B.bsums);
    scan3_k<<<(NN + 255) / 256, 256, 0, stream>>>(B.rowptr, B.bsums, B.cursor);
    csr_scatter_k<<<(NE + 255) / 256, 256, 0, stream>>>(src, dst, B.cursor, B.esrc);

    // ---- JAX keys ----
    uint32_t kd0, kd1, ke0, ke1;
    tf2x32(0u, 42u, 0u, 0u, kd0, kd1);
    tf2x32(0u, 42u, 0u, 1u, ke0, ke1);

    // ---- gc1 ----
    run_gt_layer(feat, 256, 128, wqkv1_0,                 wo1,                 true,  B.h1, B, stream);
    run_gt_layer(B.h1, 128, 128, wqkv1_r,                 wo1 + 128 * 128,     true,  B.h2, B, stream);
    run_gt_layer(B.h2, 128, 128, wqkv1_r + 3 * 128 * 128, wo1 + 2 * 128 * 128, false, B.h1, B, stream);

    norm_relu_drop_k<<<NN / 4, 256, 0, stream>>>(B.h1, B.x, kd0, kd1);

    // ---- gc2 -> mu ----
    run_gt_layer(B.x,  128, 64, wqkv2_0,               wo2,               true,  B.h1, B, stream);
    run_gt_layer(B.h1, 64,  64, wqkv2_r,               wo2 + 64 * 64,     true,  B.h2, B, stream);
    run_gt_layer(B.h2, 64,  64, wqkv2_r + 3 * 64 * 64, wo2 + 2 * 64 * 64, false, B.h1, B, stream);
    norm64_k<<<NN / 4, 256, 0, stream>>>(B.h1, B.mu);

    // ---- gc3 -> logvar ----
    run_gt_layer(B.x,  128, 64, wqkv3_0,               wo3,               true,  B.h1, B, stream);
    run_gt_layer(B.h1, 64,  64, wqkv3_r,               wo3 + 64 * 64,     true,  B.h2, B, stream);
    run_gt_layer(B.h2, 64,  64, wqkv3_r + 3 * 64 * 64, wo3 + 2 * 64 * 64, false, B.h1, B, stream);
    norm64_k<<<NN / 4, 256, 0, stream>>>(B.h1, B.lv);

    final_z_k<<<(NN * 64 + 255) / 256, 256, 0, stream>>>(B.mu, B.lv, out, ke0, ke1);
}

// Round 4
// 1529.612 us; speedup vs baseline: 8.3526x; 1.3540x over previous
//
#include <hip/hip_runtime.h>
#include <stdint.h>
#include <math.h>

#define NN 50000          // nodes
#define NE 800000         // edges
#define NH 4              // heads

// ======================= JAX threefry2x32 (partitionable mode) =======================
__host__ __device__ inline void tf2x32(uint32_t k0, uint32_t k1,
                                       uint32_t x0, uint32_t x1,
                                       uint32_t& o0, uint32_t& o1)
{
    uint32_t ks2 = k0 ^ k1 ^ 0x1BD11BDAu;
    x0 += k0; x1 += k1;
#define TF_R(r) { x0 += x1; x1 = (x1 << (r)) | (x1 >> (32 - (r))); x1 ^= x0; }
    TF_R(13) TF_R(15) TF_R(26) TF_R(6)
    x0 += k1;  x1 += ks2 + 1u;
    TF_R(17) TF_R(29) TF_R(16) TF_R(24)
    x0 += ks2; x1 += k0 + 2u;
    TF_R(13) TF_R(15) TF_R(26) TF_R(6)
    x0 += k0;  x1 += k1 + 3u;
    TF_R(17) TF_R(29) TF_R(16) TF_R(24)
    x0 += k1;  x1 += ks2 + 4u;
    TF_R(13) TF_R(15) TF_R(26) TF_R(6)
    x0 += ks2; x1 += k0 + 5u;
#undef TF_R
    o0 = x0; o1 = x1;
}

__device__ inline uint32_t jax_bits32(uint32_t k0, uint32_t k1, uint32_t idx)
{
    uint32_t a, b;
    tf2x32(k0, k1, 0u, idx, a, b);
    return a ^ b;
}

__device__ inline float jax_u01(uint32_t bits)
{
    return __uint_as_float((bits >> 9) | 0x3f800000u) - 1.0f;
}

// XLA ErfInv32 (Giles 2012)
__device__ inline float erfinv_f(float x)
{
    float w = -log1pf(-x * x);
    float p;
    if (w < 5.0f) {
        w = w - 2.5f;
        p = 2.81022636e-08f;
        p = fmaf(p, w, 3.43273939e-07f);
        p = fmaf(p, w, -3.5233877e-06f);
        p = fmaf(p, w, -4.39150654e-06f);
        p = fmaf(p, w, 0.00021858087f);
        p = fmaf(p, w, -0.00125372503f);
        p = fmaf(p, w, -0.00417768164f);
        p = fmaf(p, w, 0.246640727f);
        p = fmaf(p, w, 1.50140941f);
    } else {
        w = sqrtf(w) - 3.0f;
        p = -0.000200214257f;
        p = fmaf(p, w, 0.000100950558f);
        p = fmaf(p, w, 0.00134934322f);
        p = fmaf(p, w, -0.00367342844f);
        p = fmaf(p, w, 0.00573950773f);
        p = fmaf(p, w, -0.0076224613f);
        p = fmaf(p, w, 0.00943887047f);
        p = fmaf(p, w, 1.00167406f);
        p = fmaf(p, w, 2.83297682f);
    }
    return p * x;
}

// ======================= utility kernels =======================
__global__ __launch_bounds__(256) void fill_u32_k(uint32_t* p, uint32_t v, int n)
{
    int i = blockIdx.x * blockDim.x + threadIdx.x;
    if (i < n) p[i] = v;
}

// ======================= CSR build (once per launch) =======================
__global__ __launch_bounds__(256) void hist_k(const int* __restrict__ dst, int* __restrict__ deg)
{
    int e = blockIdx.x * blockDim.x + threadIdx.x;
    if (e < NE) atomicAdd(&deg[dst[e]], 1);
}

#define SCAN_CHUNK 1024
#define SCAN_NBLK  ((NN + SCAN_CHUNK - 1) / SCAN_CHUNK)   // 49

__global__ __launch_bounds__(256) void scan1_k(const int* __restrict__ deg,
                                               int* __restrict__ rowptr,
                                               int* __restrict__ bsums)
{
    __shared__ int lds[256];
    int b = blockIdx.x, t = threadIdx.x;
    int base = b * SCAN_CHUNK + t * 4;
    int v0 = (base + 0 < NN) ? deg[base + 0] : 0;
    int v1 = (base + 1 < NN) ? deg[base + 1] : 0;
    int v2 = (base + 2 < NN) ? deg[base + 2] : 0;
    int v3 = (base + 3 < NN) ? deg[base + 3] : 0;
    int s = v0 + v1 + v2 + v3;
    lds[t] = s;
    __syncthreads();
    for (int off = 1; off < 256; off <<= 1) {
        int x = (t >= off) ? lds[t - off] : 0;
        __syncthreads();
        lds[t] += x;
        __syncthreads();
    }
    int excl = lds[t] - s;
    if (base + 0 < NN) rowptr[base + 0] = excl;
    if (base + 1 < NN) rowptr[base + 1] = excl + v0;
    if (base + 2 < NN) rowptr[base + 2] = excl + v0 + v1;
    if (base + 3 < NN) rowptr[base + 3] = excl + v0 + v1 + v2;
    if (t == 255) bsums[b] = lds[255];
}

__global__ void scan2_k(int* bsums)
{
    if (threadIdx.x == 0 && blockIdx.x == 0) {
        int run = 0;
        for (int i = 0; i < SCAN_NBLK; i++) { int t = bsums[i]; bsums[i] = run; run += t; }
    }
}

__global__ __launch_bounds__(256) void scan3_k(int* __restrict__ rowptr,
                                               const int* __restrict__ bsums,
                                               int* __restrict__ cursor)
{
    int i = blockIdx.x * blockDim.x + threadIdx.x;
    if (i < NN) {
        int r = rowptr[i] + bsums[i / SCAN_CHUNK];
        rowptr[i] = r;
        cursor[i] = r;
    }
    if (i == 0) rowptr[NN] = NE;
}

__global__ __launch_bounds__(256) void csr_scatter_k(const int* __restrict__ src,
                                                     const int* __restrict__ dst,
                                                     int* __restrict__ cursor,
                                                     int* __restrict__ esrc)
{
    int e = blockIdx.x * blockDim.x + threadIdx.x;
    if (e >= NE) return;
    int d = dst[e];
    int pos = atomicAdd(&cursor[d], 1);
    esrc[pos] = src[e];
}

// ======================= tiled register-blocked fp32 GEMM =======================
__global__ __launch_bounds__(256) void gemm_tile_k(const float* __restrict__ A,
                                                   const float* __restrict__ W,
                                                   float* __restrict__ Cout,
                                                   int N, int K, int Cper, int Ntot,
                                                   int relu)
{
    __shared__ float As[32][65];
    __shared__ float Bs[32][64];

    const int tid = threadIdx.x;
    const int row0 = blockIdx.x * 64;
    const int nt0 = blockIdx.y * 64;
    const int b   = nt0 / Cper;
    const int c0  = nt0 - b * Cper;
    const float* Wb = W + (size_t)b * K * Cper + c0;

    const int m0 = (tid >> 4) << 2;
    const int n0 = (tid & 15) << 2;

    const int ar = tid >> 2;
    const int ak = (tid & 3) << 3;
    int arow = row0 + ar; if (arow >= N) arow = N - 1;
    const float* Arow = A + (size_t)arow * K;

    const int bk0 = tid >> 4,        bn0 = (tid & 15) << 2;
    const int bk1 = (tid + 256) >> 4, bn1 = bn0;

    float acc[4][4] = {};

    for (int k0 = 0; k0 < K; k0 += 32) {
        float4 a0 = *(const float4*)(Arow + k0 + ak);
        float4 a1 = *(const float4*)(Arow + k0 + ak + 4);
        float4 b0 = *(const float4*)(Wb + (size_t)(k0 + bk0) * Cper + bn0);
        float4 b1 = *(const float4*)(Wb + (size_t)(k0 + bk1) * Cper + bn1);
        __syncthreads();
        As[ak + 0][ar] = a0.x; As[ak + 1][ar] = a0.y; As[ak + 2][ar] = a0.z; As[ak + 3][ar] = a0.w;
        As[ak + 4][ar] = a1.x; As[ak + 5][ar] = a1.y; As[ak + 6][ar] = a1.z; As[ak + 7][ar] = a1.w;
        *(float4*)&Bs[bk0][bn0] = b0;
        *(float4*)&Bs[bk1][bn1] = b1;
        __syncthreads();
#pragma unroll
        for (int kk = 0; kk < 32; kk++) {
            float4 av = *(const float4*)&As[kk][m0];
            float4 bv = *(const float4*)&Bs[kk][n0];
            acc[0][0] = fmaf(av.x, bv.x, acc[0][0]); acc[0][1] = fmaf(av.x, bv.y, acc[0][1]);
            acc[0][2] = fmaf(av.x, bv.z, acc[0][2]); acc[0][3] = fmaf(av.x, bv.w, acc[0][3]);
            acc[1][0] = fmaf(av.y, bv.x, acc[1][0]); acc[1][1] = fmaf(av.y, bv.y, acc[1][1]);
            acc[1][2] = fmaf(av.y, bv.z, acc[1][2]); acc[1][3] = fmaf(av.y, bv.w, acc[1][3]);
            acc[2][0] = fmaf(av.z, bv.x, acc[2][0]); acc[2][1] = fmaf(av.z, bv.y, acc[2][1]);
            acc[2][2] = fmaf(av.z, bv.z, acc[2][2]); acc[2][3] = fmaf(av.z, bv.w, acc[2][3]);
            acc[3][0] = fmaf(av.w, bv.x, acc[3][0]); acc[3][1] = fmaf(av.w, bv.y, acc[3][1]);
            acc[3][2] = fmaf(av.w, bv.z, acc[3][2]); acc[3][3] = fmaf(av.w, bv.w, acc[3][3]);
        }
    }

#pragma unroll
    for (int i = 0; i < 4; i++) {
        int grow = row0 + m0 + i;
        if (grow < N) {
            float4 o;
            o.x = acc[i][0]; o.y = acc[i][1]; o.z = acc[i][2]; o.w = acc[i][3];
            if (relu) {
                o.x = fmaxf(o.x, 0.f); o.y = fmaxf(o.y, 0.f);
                o.z = fmaxf(o.z, 0.f); o.w = fmaxf(o.w, 0.f);
            }
            *(float4*)(Cout + (size_t)grow * Ntot + nt0 + n0) = o;
        }
    }
}

// ======================= wave-per-node attention (exact softmax, no atomics) =======================
// qkv layout: [N][3*OD] rows: [q(OD) | k(OD) | v(OD)]. One 64-lane wave per dst node.
// Phase 1: lanes = (16 edge-slots x 4 heads) -> scores to LDS, shuffle max/sum.
// Phase 2: lanes = (4 heads x 16 dim-slots) -> per edge one coalesced v-row read.
// Chunked at 128 edges with online rescale across chunks (exact within chunk).
template<int DH>
__global__ __launch_bounds__(64) void attn_wave_k(const float* __restrict__ qkv,
                                                  const int* __restrict__ rowptr,
                                                  const int* __restrict__ esrc,
                                                  float* __restrict__ agg,
                                                  float scale)
{
    constexpr int OD  = NH * DH;     // 128 or 64
    constexpr int STR = 3 * OD;
    constexpr int QV4 = DH / 4;      // float4s per head slice
    constexpr int F2  = OD / 64;     // floats per lane in phase 2 (2 or 1)
    constexpr int CAP = 128;

    __shared__ float s_sc[NH][CAP + 1];
    __shared__ int   s_sn[CAP];
    __shared__ float s_hdr[2 * NH];  // [0..3]=corr per head, [4..7]=l per head

    const int n    = blockIdx.x;
    const int lane = threadIdx.x;
    const int h1   = lane & 3;          // phase-1 head
    const int e    = lane >> 2;         // phase-1 edge slot (0..15)
    const int h2   = lane >> 4;         // phase-2 head
    const int d0   = (lane & 15) * F2;  // phase-2 dim offset within head

    // preload q fragment for phase-1 head
    const float4* qp = (const float4*)(qkv + (size_t)n * STR + h1 * DH);
    float4 qf[QV4];
#pragma unroll
    for (int i = 0; i < QV4; i++) qf[i] = qp[i];

    float m = -INFINITY, l = 0.0f;   // replicated per-head state (phase-1 mapping)
    float acc[F2];
#pragma unroll
    for (int i = 0; i < F2; i++) acc[i] = 0.0f;

    const int j0 = rowptr[n], j1 = rowptr[n + 1];
    const int voff = 2 * OD + h2 * DH + d0;

    for (int c0 = j0; c0 < j1; c0 += CAP) {
        const int cn = min(j1 - c0, CAP);

        // stage edge srcs
        if (lane < cn)      s_sn[lane]      = esrc[c0 + lane];
        if (lane + 64 < cn) s_sn[lane + 64] = esrc[c0 + lane + 64];
        __syncthreads();

        // ---- phase 1: scores ----
        float lm = -INFINITY;
        for (int j = e; j < cn; j += 16) {
            const int sn = s_sn[j];
            const float4* kp = (const float4*)(qkv + (size_t)sn * STR + OD + h1 * DH);
            float s = 0.0f;
#pragma unroll
            for (int i = 0; i < QV4; i++) {
                float4 kk = kp[i];
                s = fmaf(qf[i].x, kk.x, s); s = fmaf(qf[i].y, kk.y, s);
                s = fmaf(qf[i].z, kk.z, s); s = fmaf(qf[i].w, kk.w, s);
            }
            s *= scale;
            s_sc[h1][j] = s;
            lm = fmaxf(lm, s);
        }
#pragma unroll
        for (int msk = 4; msk <= 32; msk <<= 1) lm = fmaxf(lm, __shfl_xor(lm, msk, 64));
        const float mn = fmaxf(m, lm);
        const float corr = expf(m - mn);   // first chunk: exp(-inf)=0
        m = mn;

        // exponentiate own slots (no cross-lane dep yet) + partial sum
        float ls = 0.0f;
        for (int j = e; j < cn; j += 16) {
            float p = expf(s_sc[h1][j] - mn);
            s_sc[h1][j] = p;
            ls += p;
        }
#pragma unroll
        for (int msk = 4; msk <= 32; msk <<= 1) ls += __shfl_xor(ls, msk, 64);
        l = l * corr + ls;
        s_hdr[h1] = corr;               // same value from all e-lanes of head h1
        __syncthreads();

        // ---- phase 2: weights . v ----
        const float c2 = s_hdr[h2];
#pragma unroll
        for (int i = 0; i < F2; i++) acc[i] *= c2;

        int j = 0;
        for (; j + 4 <= cn; j += 4) {
            int sa = s_sn[j], sb = s_sn[j + 1], sc = s_sn[j + 2], sd = s_sn[j + 3];
            float aa = s_sc[h2][j],     ab = s_sc[h2][j + 1];
            float ac = s_sc[h2][j + 2], ad = s_sc[h2][j + 3];
            if (F2 == 2) {
                float2 va = *(const float2*)(qkv + (size_t)sa * STR + voff);
                float2 vb = *(const float2*)(qkv + (size_t)sb * STR + voff);
                float2 vc = *(const float2*)(qkv + (size_t)sc * STR + voff);
                float2 vd = *(const float2*)(qkv + (size_t)sd * STR + voff);
                acc[0] = fmaf(aa, va.x, acc[0]); acc[1] = fmaf(aa, va.y, acc[1]);
                acc[0] = fmaf(ab, vb.x, acc[0]); acc[1] = fmaf(ab, vb.y, acc[1]);
                acc[0] = fmaf(ac, vc.x, acc[0]); acc[1] = fmaf(ac, vc.y, acc[1]);
                acc[0] = fmaf(ad, vd.x, acc[0]); acc[1] = fmaf(ad, vd.y, acc[1]);
            } else {
                float va = qkv[(size_t)sa * STR + voff];
                float vb = qkv[(size_t)sb * STR + voff];
                float vc = qkv[(size_t)sc * STR + voff];
                float vd = qkv[(size_t)sd * STR + voff];
                acc[0] = fmaf(aa, va, acc[0]);
                acc[0] = fmaf(ab, vb, acc[0]);
                acc[0] = fmaf(ac, vc, acc[0]);
                acc[0] = fmaf(ad, vd, acc[0]);
            }
        }
        for (; j < cn; j++) {
            int sa = s_sn[j];
            float aa = s_sc[h2][j];
            if (F2 == 2) {
                float2 va = *(const float2*)(qkv + (size_t)sa * STR + voff);
                acc[0] = fmaf(aa, va.x, acc[0]); acc[1] = fmaf(aa, va.y, acc[1]);
            } else {
                float va = qkv[(size_t)sa * STR + voff];
                acc[0] = fmaf(aa, va, acc[0]);
            }
        }
        __syncthreads();   // LDS reusable next chunk
    }

    // publish l per head, normalize, write
    s_hdr[NH + h1] = l;
    __syncthreads();
    const float lf = s_hdr[NH + h2];
    const float inv = (lf > 0.0f) ? 1.0f / lf : 0.0f;
    float* op = agg + (size_t)n * OD + h2 * DH + d0;
    if (F2 == 2) {
        float2 o; o.x = acc[0] * inv; o.y = acc[1] * inv;
        *(float2*)op = o;
    } else {
        op[0] = acc[0] * inv;
    }
}

// ======================= norms / dropout / reparam =======================
__global__ __launch_bounds__(256) void norm_relu_drop_k(const float* __restrict__ in,
                                                        float* __restrict__ out,
                                                        uint32_t k0, uint32_t k1)
{
    int row = blockIdx.x * 4 + (threadIdx.x >> 6);
    int lane = threadIdx.x & 63;
    if (row >= NN) return;
    const float* r = in + (size_t)row * 128;
    float a = r[lane], b = r[lane + 64];
    float ss = fmaf(a, a, b * b);
#pragma unroll
    for (int m = 32; m > 0; m >>= 1) ss += __shfl_xor(ss, m, 64);
    float d = fmaxf(sqrtf(ss), 1e-12f);
    float ya = fmaxf(a / d, 0.0f);
    float yb = fmaxf(b / d, 0.0f);
    uint32_t ia = (uint32_t)row * 128u + (uint32_t)lane;
    float ua = jax_u01(jax_bits32(k0, k1, ia));
    float ub = jax_u01(jax_bits32(k0, k1, ia + 64u));
    float* o = out + (size_t)row * 128;
    o[lane]      = (ua < 0.5f) ? ya * 2.0f : 0.0f;
    o[lane + 64] = (ub < 0.5f) ? yb * 2.0f : 0.0f;
}

__global__ __launch_bounds__(256) void norm64_k(const float* __restrict__ in,
                                                float* __restrict__ out)
{
    int row = blockIdx.x * 4 + (threadIdx.x >> 6);
    int lane = threadIdx.x & 63;
    if (row >= NN) return;
    float a = in[(size_t)row * 64 + lane];
    float ss = a * a;
#pragma unroll
    for (int m = 32; m > 0; m >>= 1) ss += __shfl_xor(ss, m, 64);
    float d = fmaxf(sqrtf(ss), 1e-12f);
    out[(size_t)row * 64 + lane] = a / d;
}

__global__ __launch_bounds__(256) void final_z_k(const float* __restrict__ mu,
                                                 const float* __restrict__ lv,
                                                 float* __restrict__ out,
                                                 uint32_t k0, uint32_t k1)
{
    int i = blockIdx.x * blockDim.x + threadIdx.x;
    if (i >= NN * 64) return;
    const float LO = -0.99999994f; // nextafter(-1, 0) in f32
    float u01 = jax_u01(jax_bits32(k0, k1, (uint32_t)i));
    float u = fmaxf(LO, fmaf(u01, 2.0f, LO));
    float eps = 1.41421354f * erfinv_f(u);
    float stdv = expf(lv[i]) + 1e-12f;
    out[i] = fmaf(eps, stdv, mu[i]);
}

// ======================= host side =======================
struct Bufs {
    float* qkv;   // NN * 384  ([N][3*OD] fused layout)
    float* agg;
    float* h1;
    float* h2;
    float* x;
    float* mu;
    float* lv;
    int* rowptr;
    int* cursor;
    int* bsums;
    int* esrc;
};

static void run_gt_layer(const float* h_in, int K, int od,
                         const float* wqkv, const float* wo, bool relu,
                         float* h_out, const Bufs& B, hipStream_t stream)
{
    const int dh = od / NH;
    const float scale = 1.0f / sqrtf((float)dh);
    const int GX = (NN + 63) / 64;

    gemm_tile_k<<<dim3(GX, 3 * od / 64), 256, 0, stream>>>(h_in, wqkv, B.qkv, NN, K, od, 3 * od, 0);

    if (dh == 32)
        attn_wave_k<32><<<NN, 64, 0, stream>>>(B.qkv, B.rowptr, B.esrc, B.agg, scale);
    else
        attn_wave_k<16><<<NN, 64, 0, stream>>>(B.qkv, B.rowptr, B.esrc, B.agg, scale);

    gemm_tile_k<<<dim3(GX, od / 64), 256, 0, stream>>>(B.agg, wo, h_out, NN, od, od, od, relu ? 1 : 0);
}

extern "C" void kernel_launch(void* const* d_in, const int* in_sizes, int n_in,
                              void* d_out, int out_size, void* d_ws, size_t ws_size,
                              hipStream_t stream)
{
    const float* feat    = (const float*)d_in[0];
    const int*   src     = (const int*)d_in[1];
    const int*   dst     = (const int*)d_in[2];
    const float* wqkv1_0 = (const float*)d_in[3];
    const float* wqkv1_r = (const float*)d_in[4];
    const float* wo1     = (const float*)d_in[5];
    const float* wqkv2_0 = (const float*)d_in[6];
    const float* wqkv2_r = (const float*)d_in[7];
    const float* wo2     = (const float*)d_in[8];
    const float* wqkv3_0 = (const float*)d_in[9];
    const float* wqkv3_r = (const float*)d_in[10];
    const float* wo3     = (const float*)d_in[11];
    float* out = (float*)d_out;

    char* wp = (char*)d_ws;
    auto alloc = [&](size_t bytes) { char* p = wp; wp += (bytes + 255) & ~(size_t)255; return p; };
    Bufs B;
    B.qkv    = (float*)alloc((size_t)NN * 384 * 4);
    B.agg    = (float*)alloc((size_t)NN * 128 * 4);
    B.h1     = (float*)alloc((size_t)NN * 128 * 4);
    B.h2     = (float*)alloc((size_t)NN * 128 * 4);
    B.x      = (float*)alloc((size_t)NN * 128 * 4);
    B.mu     = (float*)alloc((size_t)NN * 64 * 4);
    B.lv     = (float*)alloc((size_t)NN * 64 * 4);
    B.rowptr = (int*)alloc((size_t)(NN + 1) * 4);
    B.cursor = (int*)alloc((size_t)NN * 4);
    B.bsums  = (int*)alloc((size_t)SCAN_NBLK * 4);
    B.esrc   = (int*)alloc((size_t)NE * 4);

    // ---- CSR build ----
    fill_u32_k<<<(NN + 255) / 256, 256, 0, stream>>>((uint32_t*)B.cursor, 0u, NN);
    hist_k<<<(NE + 255) / 256, 256, 0, stream>>>(dst, B.cursor);
    scan1_k<<<SCAN_NBLK, 256, 0, stream>>>(B.cursor, B.rowptr, B.bsums);
    scan2_k<<<1, 64, 0, stream>>>(B.bsums);
    scan3_k<<<(NN + 255) / 256, 256, 0, stream>>>(B.rowptr, B.bsums, B.cursor);
    csr_scatter_k<<<(NE + 255) / 256, 256, 0, stream>>>(src, dst, B.cursor, B.esrc);

    // ---- JAX keys ----
    uint32_t kd0, kd1, ke0, ke1;
    tf2x32(0u, 42u, 0u, 0u, kd0, kd1);
    tf2x32(0u, 42u, 0u, 1u, ke0, ke1);

    // ---- gc1 ----
    run_gt_layer(feat, 256, 128, wqkv1_0,                 wo1,                 true,  B.h1, B, stream);
    run_gt_layer(B.h1, 128, 128, wqkv1_r,                 wo1 + 128 * 128,     true,  B.h2, B, stream);
    run_gt_layer(B.h2, 128, 128, wqkv1_r + 3 * 128 * 128, wo1 + 2 * 128 * 128, false, B.h1, B, stream);

    norm_relu_drop_k<<<NN / 4, 256, 0, stream>>>(B.h1, B.x, kd0, kd1);

    // ---- gc2 -> mu ----
    run_gt_layer(B.x,  128, 64, wqkv2_0,               wo2,               true,  B.h1, B, stream);
    run_gt_layer(B.h1, 64,  64, wqkv2_r,               wo2 + 64 * 64,     true,  B.h2, B, stream);
    run_gt_layer(B.h2, 64,  64, wqkv2_r + 3 * 64 * 64, wo2 + 2 * 64 * 64, false, B.h1, B, stream);
    norm64_k<<<NN / 4, 256, 0, stream>>>(B.h1, B.mu);

    // ---- gc3 -> logvar ----
    run_gt_layer(B.x,  128, 64, wqkv3_0,               wo3,               true,  B.h1, B, stream);
    run_gt_layer(B.h1, 64,  64, wqkv3_r,               wo3 + 64 * 64,     true,  B.h2, B, stream);
    run_gt_layer(B.h2, 64,  64, wqkv3_r + 3 * 64 * 64, wo3 + 2 * 64 * 64, false, B.h1, B, stream);
    norm64_k<<<NN / 4, 256, 0, stream>>>(B.h1, B.lv);

    final_z_k<<<(NN * 64 + 255) / 256, 256, 0, stream>>>(B.mu, B.lv, out, ke0, ke1);
}

// Round 5
// 864.986 us; speedup vs baseline: 14.7705x; 1.7684x over previous
//
#include <hip/hip_runtime.h>
#include <stdint.h>
#include <math.h>

#define NN 50000          // nodes
#define NE 800000         // edges
#define NH 4              // heads

typedef __attribute__((ext_vector_type(8))) short short8;
typedef __attribute__((ext_vector_type(4))) float floatx4;

// ======================= bf16 helpers =======================
__device__ inline float bf2f(uint32_t u16)
{
    return __uint_as_float(u16 << 16);
}
__device__ inline uint16_t f2bf(float f)
{
    uint32_t u = __float_as_uint(f);
    uint32_t r = (u + 0x7fffu + ((u >> 16) & 1u)) >> 16;   // RNE
    return (uint16_t)r;
}
__device__ inline void unpk8(uint4 u, float* f)
{
    f[0] = bf2f(u.x & 0xffffu); f[1] = bf2f(u.x >> 16);
    f[2] = bf2f(u.y & 0xffffu); f[3] = bf2f(u.y >> 16);
    f[4] = bf2f(u.z & 0xffffu); f[5] = bf2f(u.z >> 16);
    f[6] = bf2f(u.w & 0xffffu); f[7] = bf2f(u.w >> 16);
}

// ======================= JAX threefry2x32 (partitionable mode) =======================
__host__ __device__ inline void tf2x32(uint32_t k0, uint32_t k1,
                                       uint32_t x0, uint32_t x1,
                                       uint32_t& o0, uint32_t& o1)
{
    uint32_t ks2 = k0 ^ k1 ^ 0x1BD11BDAu;
    x0 += k0; x1 += k1;
#define TF_R(r) { x0 += x1; x1 = (x1 << (r)) | (x1 >> (32 - (r))); x1 ^= x0; }
    TF_R(13) TF_R(15) TF_R(26) TF_R(6)
    x0 += k1;  x1 += ks2 + 1u;
    TF_R(17) TF_R(29) TF_R(16) TF_R(24)
    x0 += ks2; x1 += k0 + 2u;
    TF_R(13) TF_R(15) TF_R(26) TF_R(6)
    x0 += k0;  x1 += k1 + 3u;
    TF_R(17) TF_R(29) TF_R(16) TF_R(24)
    x0 += k1;  x1 += ks2 + 4u;
    TF_R(13) TF_R(15) TF_R(26) TF_R(6)
    x0 += ks2; x1 += k0 + 5u;
#undef TF_R
    o0 = x0; o1 = x1;
}

__device__ inline uint32_t jax_bits32(uint32_t k0, uint32_t k1, uint32_t idx)
{
    uint32_t a, b;
    tf2x32(k0, k1, 0u, idx, a, b);
    return a ^ b;
}

__device__ inline float jax_u01(uint32_t bits)
{
    return __uint_as_float((bits >> 9) | 0x3f800000u) - 1.0f;
}

// XLA ErfInv32 (Giles 2012)
__device__ inline float erfinv_f(float x)
{
    float w = -log1pf(-x * x);
    float p;
    if (w < 5.0f) {
        w = w - 2.5f;
        p = 2.81022636e-08f;
        p = fmaf(p, w, 3.43273939e-07f);
        p = fmaf(p, w, -3.5233877e-06f);
        p = fmaf(p, w, -4.39150654e-06f);
        p = fmaf(p, w, 0.00021858087f);
        p = fmaf(p, w, -0.00125372503f);
        p = fmaf(p, w, -0.00417768164f);
        p = fmaf(p, w, 0.246640727f);
        p = fmaf(p, w, 1.50140941f);
    } else {
        w = sqrtf(w) - 3.0f;
        p = -0.000200214257f;
        p = fmaf(p, w, 0.000100950558f);
        p = fmaf(p, w, 0.00134934322f);
        p = fmaf(p, w, -0.00367342844f);
        p = fmaf(p, w, 0.00573950773f);
        p = fmaf(p, w, -0.0076224613f);
        p = fmaf(p, w, 0.00943887047f);
        p = fmaf(p, w, 1.00167406f);
        p = fmaf(p, w, 2.83297682f);
    }
    return p * x;
}

// ======================= utility kernels =======================
__global__ __launch_bounds__(256) void fill_u32_k(uint32_t* p, uint32_t v, int n)
{
    int i = blockIdx.x * blockDim.x + threadIdx.x;
    if (i < n) p[i] = v;
}

__global__ __launch_bounds__(256) void f2bf_vec_k(const float* __restrict__ in,
                                                  uint16_t* __restrict__ out, int n)
{
    int i = (blockIdx.x * blockDim.x + threadIdx.x) * 4;
    if (i >= n) return;
    float4 v = *(const float4*)(in + i);
    out[i + 0] = f2bf(v.x); out[i + 1] = f2bf(v.y);
    out[i + 2] = f2bf(v.z); out[i + 3] = f2bf(v.w);
}

// ======================= weight convert: fp32 [B][K][C] -> bf16 Wt [B*C][K] =======================
struct WSeg { const float* src; int B, K, C, off; };
struct WSegs { WSeg s[18]; };

__global__ __launch_bounds__(256) void wconv_k(WSegs segs, uint16_t* __restrict__ Wt)
{
    WSeg sg = segs.s[blockIdx.y];
    int n = sg.B * sg.K * sg.C;
    int i = blockIdx.x * 256 + threadIdx.x;
    if (i >= n) return;
    int kc = sg.K * sg.C;
    int b = i / kc;
    int rr = i - b * kc;
    int k = rr / sg.C;
    int c = rr - k * sg.C;
    Wt[(size_t)sg.off + (size_t)(b * sg.C + c) * sg.K + k] = f2bf(sg.src[i]);
}

// ======================= CSR build (once per launch) =======================
__global__ __launch_bounds__(256) void hist_k(const int* __restrict__ dst, int* __restrict__ deg)
{
    int e = blockIdx.x * blockDim.x + threadIdx.x;
    if (e < NE) atomicAdd(&deg[dst[e]], 1);
}

#define SCAN_CHUNK 1024
#define SCAN_NBLK  ((NN + SCAN_CHUNK - 1) / SCAN_CHUNK)   // 49

__global__ __launch_bounds__(256) void scan1_k(const int* __restrict__ deg,
                                               int* __restrict__ rowptr,
                                               int* __restrict__ bsums)
{
    __shared__ int lds[256];
    int b = blockIdx.x, t = threadIdx.x;
    int base = b * SCAN_CHUNK + t * 4;
    int v0 = (base + 0 < NN) ? deg[base + 0] : 0;
    int v1 = (base + 1 < NN) ? deg[base + 1] : 0;
    int v2 = (base + 2 < NN) ? deg[base + 2] : 0;
    int v3 = (base + 3 < NN) ? deg[base + 3] : 0;
    int s = v0 + v1 + v2 + v3;
    lds[t] = s;
    __syncthreads();
    for (int off = 1; off < 256; off <<= 1) {
        int x = (t >= off) ? lds[t - off] : 0;
        __syncthreads();
        lds[t] += x;
        __syncthreads();
    }
    int excl = lds[t] - s;
    if (base + 0 < NN) rowptr[base + 0] = excl;
    if (base + 1 < NN) rowptr[base + 1] = excl + v0;
    if (base + 2 < NN) rowptr[base + 2] = excl + v0 + v1;
    if (base + 3 < NN) rowptr[base + 3] = excl + v0 + v1 + v2;
    if (t == 255) bsums[b] = lds[255];
}

__global__ void scan2_k(int* bsums)
{
    if (threadIdx.x == 0 && blockIdx.x == 0) {
        int run = 0;
        for (int i = 0; i < SCAN_NBLK; i++) { int t = bsums[i]; bsums[i] = run; run += t; }
    }
}

__global__ __launch_bounds__(256) void scan3_k(int* __restrict__ rowptr,
                                               const int* __restrict__ bsums,
                                               int* __restrict__ cursor)
{
    int i = blockIdx.x * blockDim.x + threadIdx.x;
    if (i < NN) {
        int r = rowptr[i] + bsums[i / SCAN_CHUNK];
        rowptr[i] = r;
        cursor[i] = r;
    }
    if (i == 0) rowptr[NN] = NE;
}

__global__ __launch_bounds__(256) void csr_scatter_k(const int* __restrict__ src,
                                                     const int* __restrict__ dst,
                                                     int* __restrict__ cursor,
                                                     int* __restrict__ esrc)
{
    int e = blockIdx.x * blockDim.x + threadIdx.x;
    if (e >= NE) return;
    int d = dst[e];
    int pos = atomicAdd(&cursor[d], 1);
    esrc[pos] = src[e];
}

// ======================= bf16 MFMA GEMM =======================
// C[N][Ntot](bf16) = A[N][K](bf16) x Wt[Ntot][K](bf16, row = output col, k-contig).
// Block: 256 thr = 4 waves, BM=64 rows (wave w -> rows 16w..16w+15).
// A staged once to LDS (padded rows); Wt staged in CH-column chunks; n-loop inside.
// MFMA 16x16x32 bf16: a-frag lane l = A[m=l&15][k=(l>>4)*8+j]; b-frag lane l =
// B[k=(l>>4)*8+j][n=l&15] (read from Wt[n][k], k-contiguous); D: row=(l>>4)*4+r, col=l&15.
template<int K, int CH>
__global__ __launch_bounds__(256) void gemm_mfma_k(const uint16_t* __restrict__ A,
                                                   const uint16_t* __restrict__ Wt,
                                                   uint16_t* __restrict__ C,
                                                   int Ntot, int relu)
{
    constexpr int KP = K + 8;        // +8 bf16 pad -> <=2-way LDS bank aliasing
    constexpr int KC = K / 8;        // 16B chunks per row
    constexpr int NT = CH / 16;
    extern __shared__ uint16_t smem[];
    uint16_t* As = smem;             // 64 x KP
    uint16_t* Ws = smem + 64 * KP;   // CH x KP

    const int tid = threadIdx.x;
    const int row0 = blockIdx.x * 64;
    const int w  = tid >> 6;
    const int l  = tid & 63;
    const int lm = l & 15;
    const int lq = l >> 4;

    // ---- stage A (64 rows x K) once ----
    for (int i = tid; i < 64 * KC; i += 256) {
        int r = i / KC, c = i - r * KC;
        int gr = row0 + r; if (gr >= NN) gr = NN - 1;
        uint4 vv = *(const uint4*)(A + (size_t)gr * K + c * 8);
        *(uint4*)(As + r * KP + c * 8) = vv;
    }

    const uint16_t* a_base = As + (16 * w + lm) * KP + lq * 8;
    const uint16_t* b_base = Ws + lm * KP + lq * 8;

    const int nchunks = Ntot / CH;
    for (int ch = 0; ch < nchunks; ch++) {
        __syncthreads();   // prior chunk consumed (and A staged, first iter)
        for (int i = tid; i < CH * KC; i += 256) {
            int r = i / KC, c = i - r * KC;
            uint4 vv = *(const uint4*)(Wt + (size_t)(ch * CH + r) * K + c * 8);
            *(uint4*)(Ws + r * KP + c * 8) = vv;
        }
        __syncthreads();

        floatx4 acc[NT];
#pragma unroll
        for (int nt = 0; nt < NT; nt++) acc[nt] = (floatx4){0.f, 0.f, 0.f, 0.f};

#pragma unroll
        for (int ks = 0; ks < K / 32; ks++) {
            short8 av = *(const short8*)(a_base + ks * 32);
#pragma unroll
            for (int nt = 0; nt < NT; nt++) {
                short8 bv = *(const short8*)(b_base + nt * 16 * KP + ks * 32);
                acc[nt] = __builtin_amdgcn_mfma_f32_16x16x32_bf16(av, bv, acc[nt], 0, 0, 0);
            }
        }

        const int rbase = row0 + 16 * w + lq * 4;
        const int cbase = ch * CH + lm;
#pragma unroll
        for (int nt = 0; nt < NT; nt++) {
#pragma unroll
            for (int r = 0; r < 4; r++) {
                int gr = rbase + r;
                if (gr < NN) {
                    float v = acc[nt][r];
                    if (relu) v = fmaxf(v, 0.0f);
                    C[(size_t)gr * Ntot + cbase + nt * 16] = f2bf(v);
                }
            }
        }
    }
}

// ======================= wave-per-node attention (bf16 qkv, fp32 math) =======================
// qkv layout: [N][3*OD] bf16 rows: [q | k | v]. One 64-lane wave per dst node.
template<int DH>
__global__ __launch_bounds__(64) void attn_wave_k(const uint16_t* __restrict__ qkv,
                                                  const int* __restrict__ rowptr,
                                                  const int* __restrict__ esrc,
                                                  uint16_t* __restrict__ agg,
                                                  float scale)
{
    constexpr int OD  = NH * DH;
    constexpr int STR = 3 * OD;
    constexpr int QU  = DH / 8;      // uint4 (8 bf16) loads per head slice
    constexpr int F2  = OD / 64;     // elems per lane in phase 2 (2 or 1)
    constexpr int CAP = 128;

    __shared__ float s_sc[NH][CAP + 1];
    __shared__ int   s_sn[CAP];
    __shared__ float s_hdr[2 * NH];

    const int n    = blockIdx.x;
    const int lane = threadIdx.x;
    const int h1   = lane & 3;
    const int e    = lane >> 2;
    const int h2   = lane >> 4;
    const int d0   = (lane & 15) * F2;

    float qf[DH];
    {
        const uint4* qp = (const uint4*)(qkv + (size_t)n * STR + h1 * DH);
#pragma unroll
        for (int i = 0; i < QU; i++) { uint4 u = qp[i]; unpk8(u, &qf[i * 8]); }
    }

    float m = -INFINITY, l = 0.0f;
    float acc[F2];
#pragma unroll
    for (int i = 0; i < F2; i++) acc[i] = 0.0f;

    const int j0 = rowptr[n], j1 = rowptr[n + 1];
    const int voff = 2 * OD + h2 * DH + d0;

    for (int c0 = j0; c0 < j1; c0 += CAP) {
        const int cn = min(j1 - c0, CAP);

        if (lane < cn)      s_sn[lane]      = esrc[c0 + lane];
        if (lane + 64 < cn) s_sn[lane + 64] = esrc[c0 + lane + 64];
        __syncthreads();

        // ---- phase 1: scores ----
        float lm = -INFINITY;
        for (int j = e; j < cn; j += 16) {
            const int sn = s_sn[j];
            const uint4* kp = (const uint4*)(qkv + (size_t)sn * STR + OD + h1 * DH);
            float s = 0.0f;
#pragma unroll
            for (int i = 0; i < QU; i++) {
                uint4 u = kp[i];
                float kf[8];
                unpk8(u, kf);
                s = fmaf(qf[i * 8 + 0], kf[0], s); s = fmaf(qf[i * 8 + 1], kf[1], s);
                s = fmaf(qf[i * 8 + 2], kf[2], s); s = fmaf(qf[i * 8 + 3], kf[3], s);
                s = fmaf(qf[i * 8 + 4], kf[4], s); s = fmaf(qf[i * 8 + 5], kf[5], s);
                s = fmaf(qf[i * 8 + 6], kf[6], s); s = fmaf(qf[i * 8 + 7], kf[7], s);
            }
            s *= scale;
            s_sc[h1][j] = s;
            lm = fmaxf(lm, s);
        }
#pragma unroll
        for (int msk = 4; msk <= 32; msk <<= 1) lm = fmaxf(lm, __shfl_xor(lm, msk, 64));
        const float mn = fmaxf(m, lm);
        const float corr = expf(m - mn);
        m = mn;

        float ls = 0.0f;
        for (int j = e; j < cn; j += 16) {
            float p = expf(s_sc[h1][j] - mn);
            s_sc[h1][j] = p;
            ls += p;
        }
#pragma unroll
        for (int msk = 4; msk <= 32; msk <<= 1) ls += __shfl_xor(ls, msk, 64);
        l = l * corr + ls;
        s_hdr[h1] = corr;
        __syncthreads();

        // ---- phase 2: weights . v ----
        const float c2 = s_hdr[h2];
#pragma unroll
        for (int i = 0; i < F2; i++) acc[i] *= c2;

        int j = 0;
        for (; j + 4 <= cn; j += 4) {
            int sa = s_sn[j], sb = s_sn[j + 1], sc = s_sn[j + 2], sd = s_sn[j + 3];
            float aa = s_sc[h2][j],     ab = s_sc[h2][j + 1];
            float ac = s_sc[h2][j + 2], ad = s_sc[h2][j + 3];
            if (F2 == 2) {
                uint32_t va = *(const uint32_t*)(qkv + (size_t)sa * STR + voff);
                uint32_t vb = *(const uint32_t*)(qkv + (size_t)sb * STR + voff);
                uint32_t vc = *(const uint32_t*)(qkv + (size_t)sc * STR + voff);
                uint32_t vd = *(const uint32_t*)(qkv + (size_t)sd * STR + voff);
                acc[0] = fmaf(aa, bf2f(va & 0xffffu), acc[0]); acc[1] = fmaf(aa, bf2f(va >> 16), acc[1]);
                acc[0] = fmaf(ab, bf2f(vb & 0xffffu), acc[0]); acc[1] = fmaf(ab, bf2f(vb >> 16), acc[1]);
                acc[0] = fmaf(ac, bf2f(vc & 0xffffu), acc[0]); acc[1] = fmaf(ac, bf2f(vc >> 16), acc[1]);
                acc[0] = fmaf(ad, bf2f(vd & 0xffffu), acc[0]); acc[1] = fmaf(ad, bf2f(vd >> 16), acc[1]);
            } else {
                acc[0] = fmaf(aa, bf2f(qkv[(size_t)sa * STR + voff]), acc[0]);
                acc[0] = fmaf(ab, bf2f(qkv[(size_t)sb * STR + voff]), acc[0]);
                acc[0] = fmaf(ac, bf2f(qkv[(size_t)sc * STR + voff]), acc[0]);
                acc[0] = fmaf(ad, bf2f(qkv[(size_t)sd * STR + voff]), acc[0]);
            }
        }
        for (; j < cn; j++) {
            int sa = s_sn[j];
            float aa = s_sc[h2][j];
            if (F2 == 2) {
                uint32_t va = *(const uint32_t*)(qkv + (size_t)sa * STR + voff);
                acc[0] = fmaf(aa, bf2f(va & 0xffffu), acc[0]); acc[1] = fmaf(aa, bf2f(va >> 16), acc[1]);
            } else {
                acc[0] = fmaf(aa, bf2f(qkv[(size_t)sa * STR + voff]), acc[0]);
            }
        }
        __syncthreads();
    }

    s_hdr[NH + h1] = l;
    __syncthreads();
    const float lf = s_hdr[NH + h2];
    const float inv = (lf > 0.0f) ? 1.0f / lf : 0.0f;
    uint16_t* op = agg + (size_t)n * OD + h2 * DH + d0;
    op[0] = f2bf(acc[0] * inv);
    if (F2 == 2) op[1] = f2bf(acc[1] * inv);
}

// ======================= norms / dropout / reparam =======================
__global__ __launch_bounds__(256) void norm_relu_drop_k(const uint16_t* __restrict__ in,
                                                        uint16_t* __restrict__ out,
                                                        uint32_t k0, uint32_t k1)
{
    int row = blockIdx.x * 4 + (threadIdx.x >> 6);
    int lane = threadIdx.x & 63;
    if (row >= NN) return;
    const uint16_t* r = in + (size_t)row * 128;
    float a = bf2f(r[lane]), b = bf2f(r[lane + 64]);
    float ss = fmaf(a, a, b * b);
#pragma unroll
    for (int m = 32; m > 0; m >>= 1) ss += __shfl_xor(ss, m, 64);
    float d = fmaxf(sqrtf(ss), 1e-12f);
    float ya = fmaxf(a / d, 0.0f);
    float yb = fmaxf(b / d, 0.0f);
    uint32_t ia = (uint32_t)row * 128u + (uint32_t)lane;
    float ua = jax_u01(jax_bits32(k0, k1, ia));
    float ub = jax_u01(jax_bits32(k0, k1, ia + 64u));
    uint16_t* o = out + (size_t)row * 128;
    o[lane]      = f2bf((ua < 0.5f) ? ya * 2.0f : 0.0f);
    o[lane + 64] = f2bf((ub < 0.5f) ? yb * 2.0f : 0.0f);
}

__global__ __launch_bounds__(256) void norm64_k(const uint16_t* __restrict__ in,
                                                float* __restrict__ out)
{
    int row = blockIdx.x * 4 + (threadIdx.x >> 6);
    int lane = threadIdx.x & 63;
    if (row >= NN) return;
    float a = bf2f(in[(size_t)row * 64 + lane]);
    float ss = a * a;
#pragma unroll
    for (int m = 32; m > 0; m >>= 1) ss += __shfl_xor(ss, m, 64);
    float d = fmaxf(sqrtf(ss), 1e-12f);
    out[(size_t)row * 64 + lane] = a / d;
}

__global__ __launch_bounds__(256) void final_z_k(const float* __restrict__ mu,
                                                 const float* __restrict__ lv,
                                                 float* __restrict__ out,
                                                 uint32_t k0, uint32_t k1)
{
    int i = blockIdx.x * blockDim.x + threadIdx.x;
    if (i >= NN * 64) return;
    const float LO = -0.99999994f; // nextafter(-1, 0) in f32
    float u01 = jax_u01(jax_bits32(k0, k1, (uint32_t)i));
    float u = fmaxf(LO, fmaf(u01, 2.0f, LO));
    float eps = 1.41421354f * erfinv_f(u);
    float stdv = expf(lv[i]) + 1e-12f;
    out[i] = fmaf(eps, stdv, mu[i]);
}

// ======================= host side =======================
struct Bufs {
    uint16_t* Wt;      // all weights, transposed bf16
    uint16_t* feat_bf; // NN*256
    uint16_t* qkv;     // NN*384
    uint16_t* agg;     // NN*128
    uint16_t* h1;
    uint16_t* h2;
    uint16_t* x;
    float* mu;
    float* lv;
    int* rowptr;
    int* cursor;
    int* bsums;
    int* esrc;
};

static void gemm_launch(int K, const uint16_t* A, const uint16_t* Wt, uint16_t* C,
                        int Ntot, int relu, hipStream_t s)
{
    int grid = (NN + 63) / 64;
    switch (K) {
    case 256: {
        size_t lds = (size_t)(64 + 32) * (256 + 8) * 2;
        gemm_mfma_k<256, 32><<<grid, 256, lds, s>>>(A, Wt, C, Ntot, relu);
        break;
    }
    case 128: {
        size_t lds = (size_t)(64 + 64) * (128 + 8) * 2;
        gemm_mfma_k<128, 64><<<grid, 256, lds, s>>>(A, Wt, C, Ntot, relu);
        break;
    }
    default: {
        size_t lds = (size_t)(64 + 64) * (64 + 8) * 2;
        gemm_mfma_k<64, 64><<<grid, 256, lds, s>>>(A, Wt, C, Ntot, relu);
        break;
    }
    }
}

static void run_gt_layer(const uint16_t* h_in, int K, int od,
                         const uint16_t* wqkv_t, const uint16_t* wo_t, bool relu,
                         uint16_t* h_out, const Bufs& B, hipStream_t stream)
{
    const int dh = od / NH;
    const float scale = 1.0f / sqrtf((float)dh);

    gemm_launch(K, h_in, wqkv_t, B.qkv, 3 * od, 0, stream);

    if (dh == 32)
        attn_wave_k<32><<<NN, 64, 0, stream>>>(B.qkv, B.rowptr, B.esrc, B.agg, scale);
    else
        attn_wave_k<16><<<NN, 64, 0, stream>>>(B.qkv, B.rowptr, B.esrc, B.agg, scale);

    gemm_launch(od, B.agg, wo_t, h_out, od, relu ? 1 : 0, stream);
}

extern "C" void kernel_launch(void* const* d_in, const int* in_sizes, int n_in,
                              void* d_out, int out_size, void* d_ws, size_t ws_size,
                              hipStream_t stream)
{
    const float* feat    = (const float*)d_in[0];
    const int*   src     = (const int*)d_in[1];
    const int*   dst     = (const int*)d_in[2];
    const float* wqkv1_0 = (const float*)d_in[3];
    const float* wqkv1_r = (const float*)d_in[4];
    const float* wo1     = (const float*)d_in[5];
    const float* wqkv2_0 = (const float*)d_in[6];
    const float* wqkv2_r = (const float*)d_in[7];
    const float* wo2     = (const float*)d_in[8];
    const float* wqkv3_0 = (const float*)d_in[9];
    const float* wqkv3_r = (const float*)d_in[10];
    const float* wo3     = (const float*)d_in[11];
    float* out = (float*)d_out;

    char* wp = (char*)d_ws;
    auto alloc = [&](size_t bytes) { char* p = wp; wp += (bytes + 255) & ~(size_t)255; return p; };

    // ---- weight segment table (order fixed) ----
    WSegs segs;
    int offs[18];
    int acc_off = 0;
    auto seg = [&](int i, const float* p, int Bc, int Kc, int Cc) {
        segs.s[i].src = p; segs.s[i].B = Bc; segs.s[i].K = Kc; segs.s[i].C = Cc;
        segs.s[i].off = acc_off; offs[i] = acc_off; acc_off += Bc * Kc * Cc;
    };
    seg(0,  wqkv1_0,                 3, 256, 128);
    seg(1,  wqkv1_r,                 3, 128, 128);
    seg(2,  wqkv1_r + 3 * 128 * 128, 3, 128, 128);
    seg(3,  wo1,                     1, 128, 128);
    seg(4,  wo1 + 128 * 128,         1, 128, 128);
    seg(5,  wo1 + 2 * 128 * 128,     1, 128, 128);
    seg(6,  wqkv2_0,                 3, 128, 64);
    seg(7,  wqkv2_r,                 3, 64, 64);
    seg(8,  wqkv2_r + 3 * 64 * 64,   3, 64, 64);
    seg(9,  wo2,                     1, 64, 64);
    seg(10, wo2 + 64 * 64,           1, 64, 64);
    seg(11, wo2 + 2 * 64 * 64,       1, 64, 64);
    seg(12, wqkv3_0,                 3, 128, 64);
    seg(13, wqkv3_r,                 3, 64, 64);
    seg(14, wqkv3_r + 3 * 64 * 64,   3, 64, 64);
    seg(15, wo3,                     1, 64, 64);
    seg(16, wo3 + 64 * 64,           1, 64, 64);
    seg(17, wo3 + 2 * 64 * 64,       1, 64, 64);

    Bufs B;
    B.Wt      = (uint16_t*)alloc((size_t)acc_off * 2);
    B.feat_bf = (uint16_t*)alloc((size_t)NN * 256 * 2);
    B.qkv     = (uint16_t*)alloc((size_t)NN * 384 * 2);
    B.agg     = (uint16_t*)alloc((size_t)NN * 128 * 2);
    B.h1      = (uint16_t*)alloc((size_t)NN * 128 * 2);
    B.h2      = (uint16_t*)alloc((size_t)NN * 128 * 2);
    B.x       = (uint16_t*)alloc((size_t)NN * 128 * 2);
    B.mu      = (float*)alloc((size_t)NN * 64 * 4);
    B.lv      = (float*)alloc((size_t)NN * 64 * 4);
    B.rowptr  = (int*)alloc((size_t)(NN + 1) * 4);
    B.cursor  = (int*)alloc((size_t)NN * 4);
    B.bsums   = (int*)alloc((size_t)SCAN_NBLK * 4);
    B.esrc    = (int*)alloc((size_t)NE * 4);

    // ---- weight + feature conversion ----
    wconv_k<<<dim3(384, 18), 256, 0, stream>>>(segs, B.Wt);
    f2bf_vec_k<<<(NN * 256 / 4 + 255) / 256, 256, 0, stream>>>(feat, B.feat_bf, NN * 256);

    // ---- CSR build ----
    fill_u32_k<<<(NN + 255) / 256, 256, 0, stream>>>((uint32_t*)B.cursor, 0u, NN);
    hist_k<<<(NE + 255) / 256, 256, 0, stream>>>(dst, B.cursor);
    scan1_k<<<SCAN_NBLK, 256, 0, stream>>>(B.cursor, B.rowptr, B.bsums);
    scan2_k<<<1, 64, 0, stream>>>(B.bsums);
    scan3_k<<<(NN + 255) / 256, 256, 0, stream>>>(B.rowptr, B.bsums, B.cursor);
    csr_scatter_k<<<(NE + 255) / 256, 256, 0, stream>>>(src, dst, B.cursor, B.esrc);

    // ---- JAX keys ----
    uint32_t kd0, kd1, ke0, ke1;
    tf2x32(0u, 42u, 0u, 0u, kd0, kd1);
    tf2x32(0u, 42u, 0u, 1u, ke0, ke1);

    // ---- gc1 ----
    run_gt_layer(B.feat_bf, 256, 128, B.Wt + offs[0], B.Wt + offs[3], true,  B.h1, B, stream);
    run_gt_layer(B.h1,      128, 128, B.Wt + offs[1], B.Wt + offs[4], true,  B.h2, B, stream);
    run_gt_layer(B.h2,      128, 128, B.Wt + offs[2], B.Wt + offs[5], false, B.h1, B, stream);

    norm_relu_drop_k<<<NN / 4, 256, 0, stream>>>(B.h1, B.x, kd0, kd1);

    // ---- gc2 -> mu ----
    run_gt_layer(B.x,  128, 64, B.Wt + offs[6], B.Wt + offs[9],  true,  B.h1, B, stream);
    run_gt_layer(B.h1, 64,  64, B.Wt + offs[7], B.Wt + offs[10], true,  B.h2, B, stream);
    run_gt_layer(B.h2, 64,  64, B.Wt + offs[8], B.Wt + offs[11], false, B.h1, B, stream);
    norm64_k<<<NN / 4, 256, 0, stream>>>(B.h1, B.mu);

    // ---- gc3 -> logvar ----
    run_gt_layer(B.x,  128, 64, B.Wt + offs[12], B.Wt + offs[15], true,  B.h1, B, stream);
    run_gt_layer(B.h1, 64,  64, B.Wt + offs[13], B.Wt + offs[16], true,  B.h2, B, stream);
    run_gt_layer(B.h2, 64,  64, B.Wt + offs[14], B.Wt + offs[17], false, B.h1, B, stream);
    norm64_k<<<NN / 4, 256, 0, stream>>>(B.h1, B.lv);

    final_z_k<<<(NN * 64 + 255) / 256, 256, 0, stream>>>(B.mu, B.lv, out, ke0, ke1);
}